// Round 1
// baseline (2220.339 us; speedup 1.0000x reference)
//
#include <hip/hip_runtime.h>
#include <math.h>

#define NIMG 1024
#define NPATCH 64
#define PDIM 192
#define KCODES 4096
#define EDIM 2048
#define VDIM 2048

// ---------------- sim GEMM + per-row top-2 argmax ----------------
// Block: 256 threads, handles one image (64 patch-rows) x all 4096 codes.
// Tiles: BN=256 codes, BK=32 over K=192. Per-thread 8x8 register tile.
#define BN 256
#define BK 32
#define TM 8
#define TN 8
#define APAD 68    // 64 rows + 4 pad (16B-aligned row stride: 272B)
#define BPAD 260   // 256 cols + 4 pad (1040B = 65*16)

__global__ __launch_bounds__(256) void sim_argmax_kernel(
    const float* __restrict__ pixels, const float* __restrict__ codebook,
    float* __restrict__ top1v, int* __restrict__ top1i,
    float* __restrict__ top2v, int* __restrict__ top2i)
{
    __shared__ float smem[BK * APAD + BK * BPAD + 64];
    float* At  = smem;                       // [BK][APAD]
    float* Bt  = smem + BK * APAD;           // [BK][BPAD]
    float* inv = smem + BK * APAD + BK * BPAD;

    const int t  = threadIdx.x;
    const int b0 = blockIdx.x;
    const float* pix = pixels + (size_t)b0 * 3 * 64 * 64;

    // per-patch inverse norms (patchify: d = ch*64 + r*8 + c)
    if (t < 64) {
        int gr = t >> 3, gc = t & 7;
        const float* pb = pix + gr * 8 * 64 + gc * 8;
        float s = 0.f;
        #pragma unroll
        for (int ch = 0; ch < 3; ++ch)
            #pragma unroll
            for (int r = 0; r < 8; ++r)
                #pragma unroll
                for (int c = 0; c < 8; ++c) {
                    float x = pb[ch * 4096 + r * 64 + c];
                    s += x * x;
                }
        inv[t] = 1.f / fmaxf(sqrtf(s), 1e-8f);
    }
    __syncthreads();

    const int ty = t >> 5, tx = t & 31;   // ty:0..7 rows, tx:0..31 cols

    float t1v[TM], t2v[TM];
    int   t1i[TM], t2i[TM];
    #pragma unroll
    for (int i = 0; i < TM; ++i) { t1v[i] = -3.4e38f; t2v[i] = -3.4e38f; t1i[i] = 0; t2i[i] = 0; }

    for (int n0 = 0; n0 < KCODES; n0 += BN) {
        float acc[TM][TN];
        #pragma unroll
        for (int i = 0; i < TM; ++i)
            #pragma unroll
            for (int j = 0; j < TN; ++j) acc[i][j] = 0.f;

        for (int k0 = 0; k0 < PDIM; k0 += BK) {
            // A tile: 32 x 64, normalized patches
            #pragma unroll
            for (int j = 0; j < 8; ++j) {
                int i = t + 256 * j;
                int row = i & 63, kk = i >> 6;
                int d = k0 + kk;
                int ch = d >> 6, r = (d >> 3) & 7, c = d & 7;
                int gr = row >> 3, gc = row & 7;
                float x = pix[ch * 4096 + (gr * 8 + r) * 64 + gc * 8 + c];
                At[kk * APAD + row] = x * inv[row];
            }
            // B tile: 32 x 256 (coalesced along codebook rows)
            #pragma unroll
            for (int j = 0; j < 32; ++j) {
                int i = t + 256 * j;
                int kk = i & 31, col = i >> 5;
                Bt[kk * BPAD + col] = codebook[(size_t)(n0 + col) * PDIM + k0 + kk];
            }
            __syncthreads();

            #pragma unroll
            for (int kk = 0; kk < BK; ++kk) {
                float av[8], bw[8];
                *(float4*)&av[0] = *(const float4*)&At[kk * APAD + ty * TM];
                *(float4*)&av[4] = *(const float4*)&At[kk * APAD + ty * TM + 4];
                *(float4*)&bw[0] = *(const float4*)&Bt[kk * BPAD + tx * TN];
                *(float4*)&bw[4] = *(const float4*)&Bt[kk * BPAD + tx * TN + 4];
                #pragma unroll
                for (int i = 0; i < TM; ++i)
                    #pragma unroll
                    for (int j = 0; j < TN; ++j)
                        acc[i][j] = fmaf(av[i], bw[j], acc[i][j]);
            }
            __syncthreads();
        }
        // fold this code tile into running top-2 (candidates arrive in increasing idx)
        #pragma unroll
        for (int i = 0; i < TM; ++i)
            #pragma unroll
            for (int j = 0; j < TN; ++j) {
                float v = acc[i][j];
                int idx = n0 + tx * TN + j;
                if (v > t1v[i]) { t2v[i] = t1v[i]; t2i[i] = t1i[i]; t1v[i] = v; t1i[i] = idx; }
                else if (v > t2v[i]) { t2v[i] = v; t2i[i] = idx; }
            }
    }

    __syncthreads();
    // cross-thread top-2 reduce: reuse smem ([64][32] x 4 arrays = 32KB < 42KB)
    float* r1v = smem;
    float* r2v = smem + 2048;
    int*   r1i = (int*)(smem + 4096);
    int*   r2i = (int*)(smem + 6144);
    #pragma unroll
    for (int i = 0; i < TM; ++i) {
        int row = ty * TM + i;
        r1v[row * 32 + tx] = t1v[i]; r1i[row * 32 + tx] = t1i[i];
        r2v[row * 32 + tx] = t2v[i]; r2i[row * 32 + tx] = t2i[i];
    }
    __syncthreads();
    if (t < 64) {
        float m1 = -3.4e38f, m2 = -3.4e38f; int mi1 = 0, mi2 = 0;
        for (int x = 0; x < 32; ++x) {
            float v; int id;
            v = r1v[t * 32 + x]; id = r1i[t * 32 + x];
            if (v > m1 || (v == m1 && id < mi1)) { m2 = m1; mi2 = mi1; m1 = v; mi1 = id; }
            else if (v > m2 || (v == m2 && id < mi2)) { m2 = v; mi2 = id; }
            v = r2v[t * 32 + x]; id = r2i[t * 32 + x];
            if (v > m1 || (v == m1 && id < mi1)) { m2 = m1; mi2 = mi1; m1 = v; mi1 = id; }
            else if (v > m2 || (v == m2 && id < mi2)) { m2 = v; mi2 = id; }
        }
        int grow = b0 * 64 + t;
        top1v[grow] = m1; top1i[grow] = mi1;
        top2v[grow] = m2; top2i[grow] = mi2;
    }
}

// ---------------- fp64 refinement of near-tie argmax ----------------
__global__ __launch_bounds__(256) void refine_kernel(
    const float* __restrict__ pixels, const float* __restrict__ codebook,
    const float* __restrict__ top1v, const int* __restrict__ top1i,
    const float* __restrict__ top2v, const int* __restrict__ top2i,
    int* __restrict__ idx_out, float* __restrict__ idxf_out)
{
    int row = blockIdx.x * 256 + threadIdx.x;
    if (row >= NIMG * NPATCH) return;
    int idx = top1i[row];
    float gap = top1v[row] - top2v[row];
    if (gap <= 2e-4f) {
        int i2 = top2i[row];
        int b = row >> 6, p = row & 63;
        int gr = p >> 3, gc = p & 7;
        const float* pb = pixels + (size_t)b * 3 * 4096 + gr * 8 * 64 + gc * 8;
        const float* c1 = codebook + (size_t)idx * PDIM;
        const float* c2 = codebook + (size_t)i2 * PDIM;
        double s1 = 0.0, s2 = 0.0;
        for (int d = 0; d < PDIM; ++d) {
            int ch = d >> 6, r = (d >> 3) & 7, c = d & 7;
            double x = (double)pb[ch * 4096 + r * 64 + c];
            s1 += x * (double)c1[d];
            s2 += x * (double)c2[d];
        }
        if (s2 > s1 || (s2 == s1 && i2 < idx)) idx = i2;
    }
    idx_out[row] = idx;
    idxf_out[row] = (float)idx;
}

// ---------------- z_real / z_local (gathered means over embeddings) ----------------
__global__ __launch_bounds__(256) void zreal_kernel(
    const float* __restrict__ emb, const int* __restrict__ idx,
    float* __restrict__ z_real, float* __restrict__ z_local)
{
    __shared__ int sidx[64];
    int b = blockIdx.x, t = threadIdx.x;
    if (t < 64) sidx[t] = idx[b * 64 + t];
    __syncthreads();
    float s[8], sl[8];
    #pragma unroll
    for (int j = 0; j < 8; ++j) { s[j] = 0.f; sl[j] = 0.f; }
    for (int p = 0; p < 64; ++p) {
        int gr = p >> 3, gc = p & 7;
        bool ag = (gr >= 3 && gr < 6 && gc >= 3 && gc < 6);
        const float* er = emb + (size_t)sidx[p] * EDIM + t * 8;
        float v[8];
        *(float4*)&v[0] = *(const float4*)er;
        *(float4*)&v[4] = *(const float4*)(er + 4);
        #pragma unroll
        for (int j = 0; j < 8; ++j) s[j] += v[j];
        if (ag) {
            #pragma unroll
            for (int j = 0; j < 8; ++j) sl[j] += v[j];
        }
    }
    float* zr = z_real + (size_t)b * EDIM + t * 8;
    float* zl = z_local + (size_t)b * EDIM + t * 8;
    #pragma unroll
    for (int j = 0; j < 8; ++j) {
        zr[j] = s[j] * (1.f / 64.f);
        zl[j] = sl[j] * (1.f / 9.f);
    }
}

// ---------------- z_vsa (XOR-bind + majority over 16 central patches) ----------------
__global__ __launch_bounds__(256) void vsa_kernel(
    const float* __restrict__ vsa, const float* __restrict__ roles,
    const int* __restrict__ idx, float* __restrict__ z_vsa)
{
    __shared__ int cidx[16];
    int b = blockIdx.x, t = threadIdx.x;
    if (t < 16) {
        int p = (2 + (t >> 2)) * 8 + 2 + (t & 3);
        cidx[t] = idx[b * 64 + p];
    }
    __syncthreads();
    float cnt[8];
    #pragma unroll
    for (int j = 0; j < 8; ++j) cnt[j] = 0.f;
    for (int cp = 0; cp < 16; ++cp) {
        int p = (2 + (cp >> 2)) * 8 + 2 + (cp & 3);
        const float* vr = vsa + (size_t)cidx[cp] * VDIM + t * 8;
        const float* pr = roles + (size_t)p * VDIM + t * 8;
        float a[8], r[8];
        *(float4*)&a[0] = *(const float4*)vr;
        *(float4*)&a[4] = *(const float4*)(vr + 4);
        *(float4*)&r[0] = *(const float4*)pr;
        *(float4*)&r[4] = *(const float4*)(pr + 4);
        #pragma unroll
        for (int j = 0; j < 8; ++j) cnt[j] += (a[j] != r[j]) ? 1.f : 0.f;
    }
    #pragma unroll
    for (int j = 0; j < 8; ++j)
        z_vsa[(size_t)b * VDIM + t * 8 + j] = cnt[j] > 8.f ? 1.f : 0.f;
}

extern "C" void kernel_launch(void* const* d_in, const int* in_sizes, int n_in,
                              void* d_out, int out_size, void* d_ws, size_t ws_size,
                              hipStream_t stream) {
    const float* pixels         = (const float*)d_in[0];
    const float* codebook       = (const float*)d_in[1];
    const float* embeddings     = (const float*)d_in[2];
    const float* codebook_vsa   = (const float*)d_in[3];
    const float* position_roles = (const float*)d_in[4];

    float* out    = (float*)d_out;
    float* z_real = out;                       // 1024*2048
    float* z_vsa  = out + 2097152;             // 1024*2048
    float* idxf   = out + 4194304;             // 1024*64
    float* z_local= out + 4259840;             // 1024*2048

    float* ws    = (float*)d_ws;
    float* top1v = ws;
    int*   top1i = (int*)(ws + 65536);
    float* top2v = ws + 131072;
    int*   top2i = (int*)(ws + 196608);
    int*   idxws = (int*)(ws + 262144);

    sim_argmax_kernel<<<NIMG, 256, 0, stream>>>(pixels, codebook, top1v, top1i, top2v, top2i);
    refine_kernel<<<(NIMG * NPATCH) / 256, 256, 0, stream>>>(pixels, codebook,
        top1v, top1i, top2v, top2i, idxws, idxf);
    zreal_kernel<<<NIMG, 256, 0, stream>>>(embeddings, idxws, z_real, z_local);
    vsa_kernel<<<NIMG, 256, 0, stream>>>(codebook_vsa, position_roles, idxws, z_vsa);
}

// Round 4
// 785.026 us; speedup vs baseline: 2.8284x; 2.8284x over previous
//
#include <hip/hip_runtime.h>
#include <hip/hip_bf16.h>
#include <math.h>

#define NIMG 1024
#define NPATCH 64
#define PDIM 192
#define KCODES 4096
#define EDIM 2048
#define VDIM 2048
#define MROWS (NIMG * NPATCH)   // 65536
#define KP 384                  // storage: [0,192)=hi, [192,384)=lo
#define KV 576                  // virtual GEMM K: A=[hi|hi|lo], B=[hi|lo|hi]
#define NSPLIT 2
#define NHALF (KCODES / NSPLIT) // 2048

typedef __attribute__((ext_vector_type(8))) short bf16x8;
typedef __attribute__((ext_vector_type(4))) float f32x4;

__device__ __forceinline__ void gload_lds16(const void* g, void* l) {
    __builtin_amdgcn_global_load_lds(
        (const __attribute__((address_space(1))) unsigned int*)g,
        (__attribute__((address_space(3))) unsigned int*)l,
        16, 0, 0);
}

__device__ __forceinline__ void merge_top2(float& v1, int& i1, float& v2, int& i2,
                                           float ov1, int oi1, float ov2, int oi2) {
    bool aw = (v1 > ov1) || (v1 == ov1 && i1 < oi1);
    float w1v = aw ? v1 : ov1;  int w1i = aw ? i1 : oi1;
    float c2v = aw ? v2 : ov2;  int c2i = aw ? i2 : oi2;   // winner's own #2
    float l1v = aw ? ov1 : v1;  int l1i = aw ? oi1 : i1;   // loser's #1
    bool bw = (c2v > l1v) || (c2v == l1v && c2i < l1i);
    v1 = w1v; i1 = w1i;
    v2 = bw ? c2v : l1v; i2 = bw ? c2i : l1i;
}

// ---------------- prep: normalized patches -> bf16 hi/lo, [65536][384] ----------------
__global__ __launch_bounds__(256) void prep_patches_kernel(
    const float* __restrict__ pixels, unsigned short* __restrict__ Abf)
{
    __shared__ float inv[64];
    const int b = blockIdx.x, t = threadIdx.x;
    const float* pix = pixels + (size_t)b * 3 * 4096;
    if (t < 64) {
        int gr = t >> 3, gc = t & 7;
        const float* pb = pix + gr * 8 * 64 + gc * 8;
        float s = 0.f;
        #pragma unroll
        for (int ch = 0; ch < 3; ++ch)
            #pragma unroll
            for (int r = 0; r < 8; ++r)
                #pragma unroll
                for (int c = 0; c < 8; ++c) {
                    float x = pb[ch * 4096 + r * 64 + c];
                    s += x * x;
                }
        inv[t] = 1.f / fmaxf(sqrtf(s), 1e-8f);
    }
    __syncthreads();
    for (int i = t; i < 64 * 192; i += 256) {
        int p = i / 192, d = i - p * 192;
        int ch = d >> 6, r = (d >> 3) & 7, c = d & 7;
        int gr = p >> 3, gc = p & 7;
        float x = pix[ch * 4096 + (gr * 8 + r) * 64 + gc * 8 + c] * inv[p];
        __hip_bfloat16 h = __float2bfloat16(x);
        float hf = __bfloat162float(h);
        __hip_bfloat16 lo = __float2bfloat16(x - hf);
        size_t row = (size_t)b * 64 + p;
        Abf[row * KP + d]       = *(unsigned short*)&h;
        Abf[row * KP + 192 + d] = *(unsigned short*)&lo;
    }
}

// ---------------- prep: codebook -> bf16 hi/lo, [4096][384] ----------------
__global__ __launch_bounds__(256) void prep_codebook_kernel(
    const float* __restrict__ cb, unsigned short* __restrict__ Bbf)
{
    int i = blockIdx.x * 256 + threadIdx.x;
    if (i >= KCODES * PDIM) return;
    int n = i / PDIM, d = i - n * PDIM;
    float x = cb[i];
    __hip_bfloat16 h = __float2bfloat16(x);
    float hf = __bfloat162float(h);
    __hip_bfloat16 lo = __float2bfloat16(x - hf);
    Bbf[(size_t)n * KP + d]       = *(unsigned short*)&h;
    Bbf[(size_t)n * KP + 192 + d] = *(unsigned short*)&lo;
}

// ---------------- bf16 MFMA GEMM + fused top-2 ----------------
// Virtual K=576: A-pattern [hi|hi|lo], B-pattern [hi|lo|hi] => hi*hi + hi*lo + lo*hi
// (drops only lo*lo ~ 2^-18; residual ~1e-5 << 2e-4 refine threshold).
// 128x128 block tile, 4 waves of 64x64 (4x4 16x16 frags), BK=32.
// LDS layout: [row][slot] with slot = kc ^ ((row>>1)&3)  (both-sides swizzle, involution)
__global__ __launch_bounds__(256) void gemm_top2_kernel(
    const unsigned short* __restrict__ A, const unsigned short* __restrict__ B,
    float* __restrict__ o1v, int* __restrict__ o1i,
    float* __restrict__ o2v, int* __restrict__ o2i)
{
    __shared__ unsigned short As[128 * 32];
    __shared__ unsigned short Bs[128 * 32];

    const int t = threadIdx.x;
    const int w = t >> 6;
    const int l = t & 63;
    const int lo4 = l & 15, hi4 = l >> 4;
    const int wr = w >> 1, wc = w & 1;
    const int m0 = blockIdx.x * 128;
    const int nbase = blockIdx.y * NHALF;

    // staging coords: issue covers LDS chunk t (16B); row=t>>2, slot=t&3
    const int srow0 = t >> 2;
    const int srow1 = 64 + (t >> 2);
    const int sslot = t & 3;
    const int kc0 = sslot ^ ((srow0 >> 1) & 3);
    const int kc1 = sslot ^ ((srow1 >> 1) & 3);

    float p1v[16], p2v[16];
    int   p1i[16], p2i[16];
    #pragma unroll
    for (int e = 0; e < 16; ++e) { p1v[e] = -3.4e38f; p2v[e] = -3.4e38f; p1i[e] = 0; p2i[e] = 0; }

    // precompute LDS read offsets (elements)
    int aoff[4], boff[4];
    #pragma unroll
    for (int rt = 0; rt < 4; ++rt) {
        int row = wr * 64 + rt * 16 + lo4;
        aoff[rt] = row * 32 + (hi4 ^ ((row >> 1) & 3)) * 8;
        int col = wc * 64 + rt * 16 + lo4;
        boff[rt] = col * 32 + (hi4 ^ ((col >> 1) & 3)) * 8;
    }

    for (int n0 = 0; n0 < NHALF; n0 += 128) {
        f32x4 acc[4][4];
        #pragma unroll
        for (int i = 0; i < 4; ++i)
            #pragma unroll
            for (int j = 0; j < 4; ++j) acc[i][j] = (f32x4){0.f, 0.f, 0.f, 0.f};

        for (int k0 = 0; k0 < KV; k0 += 32) {
            // virtual-K -> storage-K remap (wave-uniform)
            const int kA = (k0 < 192) ? k0 : (k0 - 192);   // [hi|hi|lo]
            const int kB = (k0 < 384) ? k0 : (k0 - 384);   // [hi|lo|hi]
            const unsigned short* ga0 = A + (size_t)(m0 + srow0) * KP + kA + kc0 * 8;
            const unsigned short* ga1 = A + (size_t)(m0 + srow1) * KP + kA + kc1 * 8;
            const unsigned short* gb0 = B + (size_t)(nbase + n0 + srow0) * KP + kB + kc0 * 8;
            const unsigned short* gb1 = B + (size_t)(nbase + n0 + srow1) * KP + kB + kc1 * 8;
            gload_lds16(ga0, (char*)As + w * 1024);
            gload_lds16(ga1, (char*)As + 4096 + w * 1024);
            gload_lds16(gb0, (char*)Bs + w * 1024);
            gload_lds16(gb1, (char*)Bs + 4096 + w * 1024);
            __syncthreads();

            bf16x8 af[4], bg[4];
            #pragma unroll
            for (int rt = 0; rt < 4; ++rt) af[rt] = *(const bf16x8*)&As[aoff[rt]];
            #pragma unroll
            for (int ct = 0; ct < 4; ++ct) bg[ct] = *(const bf16x8*)&Bs[boff[ct]];
            #pragma unroll
            for (int rt = 0; rt < 4; ++rt)
                #pragma unroll
                for (int ct = 0; ct < 4; ++ct)
                    acc[rt][ct] = __builtin_amdgcn_mfma_f32_16x16x32_bf16(af[rt], bg[ct], acc[rt][ct], 0, 0, 0);
            __syncthreads();
        }

        // fold candidates into per-lane top-2 (idx increasing within lane)
        #pragma unroll
        for (int rt = 0; rt < 4; ++rt)
            #pragma unroll
            for (int r = 0; r < 4; ++r) {
                const int e = rt * 4 + r;
                #pragma unroll
                for (int ct = 0; ct < 4; ++ct) {
                    float v = acc[rt][ct][r];
                    int idx = nbase + n0 + wc * 64 + ct * 16 + lo4;
                    bool gt1 = v > p1v[e];
                    bool gt2 = v > p2v[e];
                    float n2v = gt1 ? p1v[e] : (gt2 ? v : p2v[e]);
                    int   n2i = gt1 ? p1i[e] : (gt2 ? idx : p2i[e]);
                    p1v[e] = gt1 ? v : p1v[e];
                    p1i[e] = gt1 ? idx : p1i[e];
                    p2v[e] = n2v; p2i[e] = n2i;
                }
            }
    }

    // intra-wave butterfly top-2 reduce across the 16 lanes sharing each row
    // (covers only this wave's column half: cols wc*64 + ...)
    #pragma unroll
    for (int e = 0; e < 16; ++e) {
        #pragma unroll
        for (int m = 1; m < 16; m <<= 1) {
            float ov1 = __shfl_xor(p1v[e], m);
            int   oi1 = __shfl_xor(p1i[e], m);
            float ov2 = __shfl_xor(p2v[e], m);
            int   oi2 = __shfl_xor(p2i[e], m);
            merge_top2(p1v[e], p1i[e], p2v[e], p2i[e], ov1, oi1, ov2, oi2);
        }
    }

    // cross-wave (column-half) merge via LDS: [128 rows][2 halves]
    // As/Bs are dead here (all waves past the final k-loop barrier; only
    // register work since), so reuse As as scratch. 4KB needed.
    float* r1v = (float*)As;           // [128][2]
    float* r2v = r1v + 256;
    int*   r1i = (int*)(r2v + 256);
    int*   r2i = r1i + 256;
    if (lo4 == 0) {
        #pragma unroll
        for (int rt = 0; rt < 4; ++rt)
            #pragma unroll
            for (int r = 0; r < 4; ++r) {
                const int e = rt * 4 + r;
                int row = wr * 64 + rt * 16 + hi4 * 4 + r;   // row within 128-tile
                r1v[row * 2 + wc] = p1v[e]; r1i[row * 2 + wc] = p1i[e];
                r2v[row * 2 + wc] = p2v[e]; r2i[row * 2 + wc] = p2i[e];
            }
    }
    __syncthreads();
    if (t < 128) {
        float v1 = r1v[t * 2], v2 = r2v[t * 2];
        int   i1 = r1i[t * 2], i2 = r2i[t * 2];
        merge_top2(v1, i1, v2, i2, r1v[t * 2 + 1], r1i[t * 2 + 1],
                                   r2v[t * 2 + 1], r2i[t * 2 + 1]);
        int grow = blockIdx.y * MROWS + m0 + t;
        o1v[grow] = v1; o1i[grow] = i1;
        o2v[grow] = v2; o2i[grow] = i2;
    }
}

// ---------------- merge splits + fp64 refinement of near-tie argmax ----------------
__global__ __launch_bounds__(256) void refine_kernel(
    const float* __restrict__ pixels, const float* __restrict__ codebook,
    const float* __restrict__ o1v, const int* __restrict__ o1i,
    const float* __restrict__ o2v, const int* __restrict__ o2i,
    int* __restrict__ idx_out, float* __restrict__ idxf_out)
{
    int row = blockIdx.x * 256 + threadIdx.x;
    if (row >= MROWS) return;
    float v1 = o1v[row], v2 = o2v[row];
    int   i1 = o1i[row], i2 = o2i[row];
    merge_top2(v1, i1, v2, i2, o1v[MROWS + row], o1i[MROWS + row],
                               o2v[MROWS + row], o2i[MROWS + row]);
    int idx = i1;
    if (v1 - v2 <= 2e-4f) {
        int b = row >> 6, p = row & 63;
        int gr = p >> 3, gc = p & 7;
        const float* pb = pixels + (size_t)b * 3 * 4096 + gr * 8 * 64 + gc * 8;
        const float* c1 = codebook + (size_t)i1 * PDIM;
        const float* c2 = codebook + (size_t)i2 * PDIM;
        double s1 = 0.0, s2 = 0.0;
        for (int d = 0; d < PDIM; ++d) {
            int ch = d >> 6, r = (d >> 3) & 7, c = d & 7;
            double x = (double)pb[ch * 4096 + r * 64 + c];
            s1 += x * (double)c1[d];
            s2 += x * (double)c2[d];
        }
        if (s2 > s1 || (s2 == s1 && i2 < i1)) idx = i2;
    }
    idx_out[row] = idx;
    idxf_out[row] = (float)idx;
}

// ---------------- z_real / z_local ----------------
__global__ __launch_bounds__(256) void zreal_kernel(
    const float* __restrict__ emb, const int* __restrict__ idx,
    float* __restrict__ z_real, float* __restrict__ z_local)
{
    __shared__ int sidx[64];
    int b = blockIdx.x, t = threadIdx.x;
    if (t < 64) sidx[t] = idx[b * 64 + t];
    __syncthreads();
    float s[8], sl[8];
    #pragma unroll
    for (int j = 0; j < 8; ++j) { s[j] = 0.f; sl[j] = 0.f; }
    for (int p = 0; p < 64; ++p) {
        int gr = p >> 3, gc = p & 7;
        bool ag = (gr >= 3 && gr < 6 && gc >= 3 && gc < 6);
        const float* er = emb + (size_t)sidx[p] * EDIM + t * 8;
        float v[8];
        *(float4*)&v[0] = *(const float4*)er;
        *(float4*)&v[4] = *(const float4*)(er + 4);
        #pragma unroll
        for (int j = 0; j < 8; ++j) s[j] += v[j];
        if (ag) {
            #pragma unroll
            for (int j = 0; j < 8; ++j) sl[j] += v[j];
        }
    }
    float* zr = z_real + (size_t)b * EDIM + t * 8;
    float* zl = z_local + (size_t)b * EDIM + t * 8;
    #pragma unroll
    for (int j = 0; j < 8; ++j) {
        zr[j] = s[j] * (1.f / 64.f);
        zl[j] = sl[j] * (1.f / 9.f);
    }
}

// ---------------- z_vsa ----------------
__global__ __launch_bounds__(256) void vsa_kernel(
    const float* __restrict__ vsa, const float* __restrict__ roles,
    const int* __restrict__ idx, float* __restrict__ z_vsa)
{
    __shared__ int cidx[16];
    int b = blockIdx.x, t = threadIdx.x;
    if (t < 16) {
        int p = (2 + (t >> 2)) * 8 + 2 + (t & 3);
        cidx[t] = idx[b * 64 + p];
    }
    __syncthreads();
    float cnt[8];
    #pragma unroll
    for (int j = 0; j < 8; ++j) cnt[j] = 0.f;
    for (int cp = 0; cp < 16; ++cp) {
        int p = (2 + (cp >> 2)) * 8 + 2 + (cp & 3);
        const float* vr = vsa + (size_t)cidx[cp] * VDIM + t * 8;
        const float* pr = roles + (size_t)p * VDIM + t * 8;
        float a[8], r[8];
        *(float4*)&a[0] = *(const float4*)vr;
        *(float4*)&a[4] = *(const float4*)(vr + 4);
        *(float4*)&r[0] = *(const float4*)pr;
        *(float4*)&r[4] = *(const float4*)(pr + 4);
        #pragma unroll
        for (int j = 0; j < 8; ++j) cnt[j] += (a[j] != r[j]) ? 1.f : 0.f;
    }
    #pragma unroll
    for (int j = 0; j < 8; ++j)
        z_vsa[(size_t)b * VDIM + t * 8 + j] = cnt[j] > 8.f ? 1.f : 0.f;
}

extern "C" void kernel_launch(void* const* d_in, const int* in_sizes, int n_in,
                              void* d_out, int out_size, void* d_ws, size_t ws_size,
                              hipStream_t stream) {
    const float* pixels         = (const float*)d_in[0];
    const float* codebook       = (const float*)d_in[1];
    const float* embeddings     = (const float*)d_in[2];
    const float* codebook_vsa   = (const float*)d_in[3];
    const float* position_roles = (const float*)d_in[4];

    float* out     = (float*)d_out;
    float* z_real  = out;                 // 1024*2048
    float* z_vsa   = out + 2097152;       // 1024*2048
    float* idxf    = out + 4194304;       // 1024*64
    float* z_local = out + 4259840;       // 1024*2048

    char* ws = (char*)d_ws;
    unsigned short* Abf = (unsigned short*)(ws);                     // 50331648 B
    unsigned short* Bbf = (unsigned short*)(ws + 50331648);          //  3145728 B
    float* o1v = (float*)(ws + 53477376);                            //   524288 B
    int*   o1i = (int*)  (ws + 54001664);
    float* o2v = (float*)(ws + 54525952);
    int*   o2i = (int*)  (ws + 55050240);
    int*   idxws = (int*)(ws + 55574528);                            //   262144 B

    prep_patches_kernel<<<NIMG, 256, 0, stream>>>(pixels, Abf);
    prep_codebook_kernel<<<(KCODES * PDIM + 255) / 256, 256, 0, stream>>>(codebook, Bbf);

    dim3 ggrid(MROWS / 128, NSPLIT);
    gemm_top2_kernel<<<ggrid, 256, 0, stream>>>(Abf, Bbf, o1v, o1i, o2v, o2i);

    refine_kernel<<<MROWS / 256, 256, 0, stream>>>(pixels, codebook,
        o1v, o1i, o2v, o2i, idxws, idxf);
    zreal_kernel<<<NIMG, 256, 0, stream>>>(embeddings, idxws, z_real, z_local);
    vsa_kernel<<<NIMG, 256, 0, stream>>>(codebook_vsa, position_roles, idxws, z_vsa);
}

// Round 5
// 549.233 us; speedup vs baseline: 4.0426x; 1.4293x over previous
//
#include <hip/hip_runtime.h>
#include <hip/hip_bf16.h>
#include <math.h>

#define NIMG 1024
#define NPATCH 64
#define PDIM 192
#define KCODES 4096
#define EDIM 2048
#define VDIM 2048
#define MROWS (NIMG * NPATCH)   // 65536
#define KP 384                  // storage: [0,192)=hi, [192,384)=lo
#define KV 576                  // virtual GEMM K: A=[hi|hi|lo], B=[hi|lo|hi]
#define NSPLIT 2
#define NHALF (KCODES / NSPLIT) // 2048
#define NT (NHALF / 128)        // 16 column tiles per block
#define NK (KV / 32)            // 18 K-steps per column tile

typedef __attribute__((ext_vector_type(8))) short bf16x8;
typedef __attribute__((ext_vector_type(4))) float f32x4;

__device__ __forceinline__ void gload_lds16(const void* g, void* l) {
    __builtin_amdgcn_global_load_lds(
        (const __attribute__((address_space(1))) unsigned int*)g,
        (__attribute__((address_space(3))) unsigned int*)l,
        16, 0, 0);
}

__device__ __forceinline__ void merge_top2(float& v1, int& i1, float& v2, int& i2,
                                           float ov1, int oi1, float ov2, int oi2) {
    bool aw = (v1 > ov1) || (v1 == ov1 && i1 < oi1);
    float w1v = aw ? v1 : ov1;  int w1i = aw ? i1 : oi1;
    float c2v = aw ? v2 : ov2;  int c2i = aw ? i2 : oi2;   // winner's own #2
    float l1v = aw ? ov1 : v1;  int l1i = aw ? oi1 : i1;   // loser's #1
    bool bw = (c2v > l1v) || (c2v == l1v && c2i < l1i);
    v1 = w1v; i1 = w1i;
    v2 = bw ? c2v : l1v; i2 = bw ? c2i : l1i;
}

// packed-key top-2 fold: 3 VALU (min_i32 + 2 max_i32)
__device__ __forceinline__ void kfold(int& t1, int& t2, int key) {
    int m = (key < t1) ? key : t1;
    t2 = (t2 > m) ? t2 : m;
    t1 = (t1 > key) ? t1 : key;
}

// ---------------- prep: normalized patches -> bf16 hi/lo, [65536][384] ----------------
__global__ __launch_bounds__(256) void prep_patches_kernel(
    const float* __restrict__ pixels, unsigned short* __restrict__ Abf)
{
    __shared__ float inv[64];
    const int b = blockIdx.x, t = threadIdx.x;
    const float* pix = pixels + (size_t)b * 3 * 4096;
    if (t < 64) {
        int gr = t >> 3, gc = t & 7;
        const float* pb = pix + gr * 8 * 64 + gc * 8;
        float s = 0.f;
        #pragma unroll
        for (int ch = 0; ch < 3; ++ch)
            #pragma unroll
            for (int r = 0; r < 8; ++r)
                #pragma unroll
                for (int c = 0; c < 8; ++c) {
                    float x = pb[ch * 4096 + r * 64 + c];
                    s += x * x;
                }
        inv[t] = 1.f / fmaxf(sqrtf(s), 1e-8f);
    }
    __syncthreads();
    for (int i = t; i < 64 * 192; i += 256) {
        int p = i / 192, d = i - p * 192;
        int ch = d >> 6, r = (d >> 3) & 7, c = d & 7;
        int gr = p >> 3, gc = p & 7;
        float x = pix[ch * 4096 + (gr * 8 + r) * 64 + gc * 8 + c] * inv[p];
        __hip_bfloat16 h = __float2bfloat16(x);
        float hf = __bfloat162float(h);
        __hip_bfloat16 lo = __float2bfloat16(x - hf);
        size_t row = (size_t)b * 64 + p;
        Abf[row * KP + d]       = *(unsigned short*)&h;
        Abf[row * KP + 192 + d] = *(unsigned short*)&lo;
    }
}

// ---------------- prep: codebook -> bf16 hi/lo, [4096][384] ----------------
__global__ __launch_bounds__(256) void prep_codebook_kernel(
    const float* __restrict__ cb, unsigned short* __restrict__ Bbf)
{
    int i = blockIdx.x * 256 + threadIdx.x;
    if (i >= KCODES * PDIM) return;
    int n = i / PDIM, d = i - n * PDIM;
    float x = cb[i];
    __hip_bfloat16 h = __float2bfloat16(x);
    float hf = __bfloat162float(h);
    __hip_bfloat16 lo = __float2bfloat16(x - hf);
    Bbf[(size_t)n * KP + d]       = *(unsigned short*)&h;
    Bbf[(size_t)n * KP + 192 + d] = *(unsigned short*)&lo;
}

// ---------------- bf16 MFMA GEMM + fused packed-key top-2 ----------------
// Virtual K=576: A-pattern [hi|hi|lo], B-pattern [hi|lo|hi] => hi*hi + hi*lo + lo*hi.
// 128x128 block tile, 4 waves of 64x64, BK=32; 2-phase double-buffered LDS
// (STAGE next tile before computing current; single barrier per step).
__global__ __launch_bounds__(256) void gemm_top2_kernel(
    const unsigned short* __restrict__ A, const unsigned short* __restrict__ B,
    float* __restrict__ o1v, int* __restrict__ o1i,
    float* __restrict__ o2v, int* __restrict__ o2i)
{
    __shared__ unsigned short As[2][128 * 32];
    __shared__ unsigned short Bs[2][128 * 32];

    const int t = threadIdx.x;
    const int w = t >> 6;
    const int l = t & 63;
    const int lo4 = l & 15, hi4 = l >> 4;
    const int wr = w >> 1, wc = w & 1;
    const int m0 = blockIdx.x * 128;
    const int nbase = blockIdx.y * NHALF;

    // staging coords: thread t covers LDS chunk t (16B); row=t>>2, slot=t&3
    const int srow0 = t >> 2;
    const int srow1 = 64 + (t >> 2);
    const int sslot = t & 3;
    const int kc0 = sslot ^ ((srow0 >> 1) & 3);
    const int kc1 = sslot ^ ((srow1 >> 1) & 3);

    // loop-invariant global base pointers
    const unsigned short* a0b = A + (size_t)(m0 + srow0) * KP + kc0 * 8;
    const unsigned short* a1b = A + (size_t)(m0 + srow1) * KP + kc1 * 8;
    const unsigned short* b0b = B + (size_t)(nbase + srow0) * KP + kc0 * 8;
    const unsigned short* b1b = B + (size_t)(nbase + srow1) * KP + kc1 * 8;

    int t1k[16], t2k[16];
    #pragma unroll
    for (int e = 0; e < 16; ++e) { t1k[e] = (int)0x80000000; t2k[e] = (int)0x80000000; }

    // LDS read offsets (elements)
    int aoff[4], boff[4];
    #pragma unroll
    for (int rt = 0; rt < 4; ++rt) {
        int row = wr * 64 + rt * 16 + lo4;
        aoff[rt] = row * 32 + (hi4 ^ ((row >> 1) & 3)) * 8;
        int col = wc * 64 + rt * 16 + lo4;
        boff[rt] = col * 32 + (hi4 ^ ((col >> 1) & 3)) * 8;
    }

    // prologue: stage (nt=0, kk=0) into buf 0
    gload_lds16(a0b, (char*)As[0] + w * 1024);
    gload_lds16(a1b, (char*)As[0] + 4096 + w * 1024);
    gload_lds16(b0b, (char*)Bs[0] + w * 1024);
    gload_lds16(b1b, (char*)Bs[0] + 4096 + w * 1024);
    __syncthreads();   // compiler emits vmcnt(0) before s_barrier

    int cur = 0;
    for (int nt = 0; nt < NT; ++nt) {
        f32x4 acc[4][4];
        #pragma unroll
        for (int i = 0; i < 4; ++i)
            #pragma unroll
            for (int j = 0; j < 4; ++j) acc[i][j] = (f32x4){0.f, 0.f, 0.f, 0.f};

        for (int kk = 0; kk < NK; ++kk) {
            // ---- prefetch next step into alternate buffer ----
            int nn = nt, nk = kk + 1;
            if (nk == NK) { nk = 0; ++nn; }
            if (nn < NT) {
                const int k0n = nk * 32;
                const int kAn = (k0n < 192) ? k0n : (k0n - 192);   // [hi|hi|lo]
                const int kBn = (k0n < 384) ? k0n : (k0n - 384);   // [hi|lo|hi]
                const int bo  = nn * 128 * KP + kBn;
                const int nxt = cur ^ 1;
                gload_lds16(a0b + kAn, (char*)As[nxt] + w * 1024);
                gload_lds16(a1b + kAn, (char*)As[nxt] + 4096 + w * 1024);
                gload_lds16(b0b + bo,  (char*)Bs[nxt] + w * 1024);
                gload_lds16(b1b + bo,  (char*)Bs[nxt] + 4096 + w * 1024);
            }

            // ---- compute current buffer ----
            bf16x8 af[4], bg[4];
            #pragma unroll
            for (int rt = 0; rt < 4; ++rt) af[rt] = *(const bf16x8*)&As[cur][aoff[rt]];
            #pragma unroll
            for (int ct = 0; ct < 4; ++ct) bg[ct] = *(const bf16x8*)&Bs[cur][boff[ct]];
            #pragma unroll
            for (int rt = 0; rt < 4; ++rt)
                #pragma unroll
                for (int ct = 0; ct < 4; ++ct)
                    acc[rt][ct] = __builtin_amdgcn_mfma_f32_16x16x32_bf16(af[rt], bg[ct], acc[rt][ct], 0, 0, 0);

            // ---- packed-key fold on last K-step of this column tile ----
            if (kk == NK - 1) {
                #pragma unroll
                for (int ct = 0; ct < 4; ++ct) {
                    const int inv6 = 0x3F ^ ((nt << 2) | ct);   // wave-uniform
                    #pragma unroll
                    for (int rt = 0; rt < 4; ++rt)
                        #pragma unroll
                        for (int r = 0; r < 4; ++r) {
                            int key = (__float_as_int(acc[rt][ct][r]) & ~0x3F) | inv6;
                            kfold(t1k[rt * 4 + r], t2k[rt * 4 + r], key);
                        }
                }
            }
            __syncthreads();   // vmcnt(0)+barrier: next-stage loads landed, reads done
            cur ^= 1;
        }
    }

    // ---- decode keys -> (value, index) ----
    float p1v[16], p2v[16];
    int   p1i[16], p2i[16];
    #pragma unroll
    for (int e = 0; e < 16; ++e) {
        p1v[e] = __int_as_float(t1k[e] & ~0x3F);
        int lo1 = 0x3F ^ (t1k[e] & 0x3F);
        p1i[e] = nbase + ((lo1 >> 2) << 7) + wc * 64 + ((lo1 & 3) << 4) + lo4;
        p2v[e] = __int_as_float(t2k[e] & ~0x3F);
        int lo2 = 0x3F ^ (t2k[e] & 0x3F);
        p2i[e] = nbase + ((lo2 >> 2) << 7) + wc * 64 + ((lo2 & 3) << 4) + lo4;
    }

    // intra-wave butterfly top-2 reduce across the 16 lanes sharing each row
    #pragma unroll
    for (int e = 0; e < 16; ++e) {
        #pragma unroll
        for (int m = 1; m < 16; m <<= 1) {
            float ov1 = __shfl_xor(p1v[e], m);
            int   oi1 = __shfl_xor(p1i[e], m);
            float ov2 = __shfl_xor(p2v[e], m);
            int   oi2 = __shfl_xor(p2i[e], m);
            merge_top2(p1v[e], p1i[e], p2v[e], p2i[e], ov1, oi1, ov2, oi2);
        }
    }

    // cross-wave (column-half) merge via LDS scratch (reuse As; all reads done)
    float* r1v = (float*)As;           // [128][2]
    float* r2v = r1v + 256;
    int*   r1i = (int*)(r2v + 256);
    int*   r2i = r1i + 256;
    if (lo4 == 0) {
        #pragma unroll
        for (int rt = 0; rt < 4; ++rt)
            #pragma unroll
            for (int r = 0; r < 4; ++r) {
                const int e = rt * 4 + r;
                int row = wr * 64 + rt * 16 + hi4 * 4 + r;   // row within 128-tile
                r1v[row * 2 + wc] = p1v[e]; r1i[row * 2 + wc] = p1i[e];
                r2v[row * 2 + wc] = p2v[e]; r2i[row * 2 + wc] = p2i[e];
            }
    }
    __syncthreads();
    if (t < 128) {
        float v1 = r1v[t * 2], v2 = r2v[t * 2];
        int   i1 = r1i[t * 2], i2 = r2i[t * 2];
        merge_top2(v1, i1, v2, i2, r1v[t * 2 + 1], r1i[t * 2 + 1],
                                   r2v[t * 2 + 1], r2i[t * 2 + 1]);
        int grow = blockIdx.y * MROWS + m0 + t;
        o1v[grow] = v1; o1i[grow] = i1;
        o2v[grow] = v2; o2i[grow] = i2;
    }
}

// ---------------- merge splits + fp64 refinement of near-tie argmax ----------------
__global__ __launch_bounds__(256) void refine_kernel(
    const float* __restrict__ pixels, const float* __restrict__ codebook,
    const float* __restrict__ o1v, const int* __restrict__ o1i,
    const float* __restrict__ o2v, const int* __restrict__ o2i,
    int* __restrict__ idx_out, float* __restrict__ idxf_out)
{
    int row = blockIdx.x * 256 + threadIdx.x;
    if (row >= MROWS) return;
    float v1 = o1v[row], v2 = o2v[row];
    int   i1 = o1i[row], i2 = o2i[row];
    merge_top2(v1, i1, v2, i2, o1v[MROWS + row], o1i[MROWS + row],
                               o2v[MROWS + row], o2i[MROWS + row]);
    int idx = i1;
    if (v1 - v2 <= 2e-4f) {
        int b = row >> 6, p = row & 63;
        int gr = p >> 3, gc = p & 7;
        const float* pb = pixels + (size_t)b * 3 * 4096 + gr * 8 * 64 + gc * 8;
        const float* c1 = codebook + (size_t)i1 * PDIM;
        const float* c2 = codebook + (size_t)i2 * PDIM;
        double s1 = 0.0, s2 = 0.0;
        for (int d = 0; d < PDIM; ++d) {
            int ch = d >> 6, r = (d >> 3) & 7, c = d & 7;
            double x = (double)pb[ch * 4096 + r * 64 + c];
            s1 += x * (double)c1[d];
            s2 += x * (double)c2[d];
        }
        if (s2 > s1 || (s2 == s1 && i2 < i1)) idx = i2;
    }
    idx_out[row] = idx;
    idxf_out[row] = (float)idx;
}

// ---------------- z_real / z_local ----------------
__global__ __launch_bounds__(256) void zreal_kernel(
    const float* __restrict__ emb, const int* __restrict__ idx,
    float* __restrict__ z_real, float* __restrict__ z_local)
{
    __shared__ int sidx[64];
    int b = blockIdx.x, t = threadIdx.x;
    if (t < 64) sidx[t] = idx[b * 64 + t];
    __syncthreads();
    float s[8], sl[8];
    #pragma unroll
    for (int j = 0; j < 8; ++j) { s[j] = 0.f; sl[j] = 0.f; }
    for (int p = 0; p < 64; ++p) {
        int gr = p >> 3, gc = p & 7;
        bool ag = (gr >= 3 && gr < 6 && gc >= 3 && gc < 6);
        const float* er = emb + (size_t)sidx[p] * EDIM + t * 8;
        float v[8];
        *(float4*)&v[0] = *(const float4*)er;
        *(float4*)&v[4] = *(const float4*)(er + 4);
        #pragma unroll
        for (int j = 0; j < 8; ++j) s[j] += v[j];
        if (ag) {
            #pragma unroll
            for (int j = 0; j < 8; ++j) sl[j] += v[j];
        }
    }
    float* zr = z_real + (size_t)b * EDIM + t * 8;
    float* zl = z_local + (size_t)b * EDIM + t * 8;
    #pragma unroll
    for (int j = 0; j < 8; ++j) {
        zr[j] = s[j] * (1.f / 64.f);
        zl[j] = sl[j] * (1.f / 9.f);
    }
}

// ---------------- z_vsa ----------------
__global__ __launch_bounds__(256) void vsa_kernel(
    const float* __restrict__ vsa, const float* __restrict__ roles,
    const int* __restrict__ idx, float* __restrict__ z_vsa)
{
    __shared__ int cidx[16];
    int b = blockIdx.x, t = threadIdx.x;
    if (t < 16) {
        int p = (2 + (t >> 2)) * 8 + 2 + (t & 3);
        cidx[t] = idx[b * 64 + p];
    }
    __syncthreads();
    float cnt[8];
    #pragma unroll
    for (int j = 0; j < 8; ++j) cnt[j] = 0.f;
    for (int cp = 0; cp < 16; ++cp) {
        int p = (2 + (cp >> 2)) * 8 + 2 + (cp & 3);
        const float* vr = vsa + (size_t)cidx[cp] * VDIM + t * 8;
        const float* pr = roles + (size_t)p * VDIM + t * 8;
        float a[8], r[8];
        *(float4*)&a[0] = *(const float4*)vr;
        *(float4*)&a[4] = *(const float4*)(vr + 4);
        *(float4*)&r[0] = *(const float4*)pr;
        *(float4*)&r[4] = *(const float4*)(pr + 4);
        #pragma unroll
        for (int j = 0; j < 8; ++j) cnt[j] += (a[j] != r[j]) ? 1.f : 0.f;
    }
    #pragma unroll
    for (int j = 0; j < 8; ++j)
        z_vsa[(size_t)b * VDIM + t * 8 + j] = cnt[j] > 8.f ? 1.f : 0.f;
}

extern "C" void kernel_launch(void* const* d_in, const int* in_sizes, int n_in,
                              void* d_out, int out_size, void* d_ws, size_t ws_size,
                              hipStream_t stream) {
    const float* pixels         = (const float*)d_in[0];
    const float* codebook       = (const float*)d_in[1];
    const float* embeddings     = (const float*)d_in[2];
    const float* codebook_vsa   = (const float*)d_in[3];
    const float* position_roles = (const float*)d_in[4];

    float* out     = (float*)d_out;
    float* z_real  = out;                 // 1024*2048
    float* z_vsa   = out + 2097152;       // 1024*2048
    float* idxf    = out + 4194304;       // 1024*64
    float* z_local = out + 4259840;       // 1024*2048

    char* ws = (char*)d_ws;
    unsigned short* Abf = (unsigned short*)(ws);                     // 50331648 B
    unsigned short* Bbf = (unsigned short*)(ws + 50331648);          //  3145728 B
    float* o1v = (float*)(ws + 53477376);                            //   524288 B
    int*   o1i = (int*)  (ws + 54001664);
    float* o2v = (float*)(ws + 54525952);
    int*   o2i = (int*)  (ws + 55050240);
    int*   idxws = (int*)(ws + 55574528);                            //   262144 B

    prep_patches_kernel<<<NIMG, 256, 0, stream>>>(pixels, Abf);
    prep_codebook_kernel<<<(KCODES * PDIM + 255) / 256, 256, 0, stream>>>(codebook, Bbf);

    dim3 ggrid(MROWS / 128, NSPLIT);
    gemm_top2_kernel<<<ggrid, 256, 0, stream>>>(Abf, Bbf, o1v, o1i, o2v, o2i);

    refine_kernel<<<MROWS / 256, 256, 0, stream>>>(pixels, codebook,
        o1v, o1i, o2v, o2i, idxws, idxf);
    zreal_kernel<<<NIMG, 256, 0, stream>>>(embeddings, idxws, z_real, z_local);
    vsa_kernel<<<NIMG, 256, 0, stream>>>(codebook_vsa, position_roles, idxws, z_vsa);
}

// Round 6
// 454.072 us; speedup vs baseline: 4.8898x; 1.2096x over previous
//
#include <hip/hip_runtime.h>
#include <hip/hip_bf16.h>
#include <math.h>

#define NIMG 1024
#define NPATCH 64
#define PDIM 192
#define KCODES 4096
#define EDIM 2048
#define VDIM 2048
#define MROWS (NIMG * NPATCH)   // 65536
#define KP 384                  // storage: [0,192)=hi, [192,384)=lo
#define NKS 18                  // K-steps (BK=32) per column tile: virtual K=576
#define NCT 16                  // column tiles of 256 codes
#define SSTEPS (NCT * NKS)      // 288 flat stages

typedef __attribute__((ext_vector_type(8))) short bf16x8;
typedef __attribute__((ext_vector_type(4))) float f32x4;

__device__ __forceinline__ void gload_lds16(const void* g, void* l) {
    __builtin_amdgcn_global_load_lds(
        (const __attribute__((address_space(1))) unsigned int*)g,
        (__attribute__((address_space(3))) unsigned int*)l,
        16, 0, 0);
}

__device__ __forceinline__ void merge_top2(float& v1, int& i1, float& v2, int& i2,
                                           float ov1, int oi1, float ov2, int oi2) {
    bool aw = (v1 > ov1) || (v1 == ov1 && i1 < oi1);
    float w1v = aw ? v1 : ov1;  int w1i = aw ? i1 : oi1;
    float c2v = aw ? v2 : ov2;  int c2i = aw ? i2 : oi2;   // winner's own #2
    float l1v = aw ? ov1 : v1;  int l1i = aw ? oi1 : i1;   // loser's #1
    bool bw = (c2v > l1v) || (c2v == l1v && c2i < l1i);
    v1 = w1v; i1 = w1i;
    v2 = bw ? c2v : l1v; i2 = bw ? c2i : l1i;
}

// packed-key top-2 fold: 3 VALU (min_i32 + 2 max_i32)
__device__ __forceinline__ void kfold(int& t1, int& t2, int key) {
    int m = (key < t1) ? key : t1;
    t2 = (t2 > m) ? t2 : m;
    t1 = (t1 > key) ? t1 : key;
}

// ---------------- prep: normalized patches -> bf16 hi/lo, [65536][384] ----------------
__global__ __launch_bounds__(256) void prep_patches_kernel(
    const float* __restrict__ pixels, unsigned short* __restrict__ Abf)
{
    __shared__ float inv[64];
    const int b = blockIdx.x, t = threadIdx.x;
    const float* pix = pixels + (size_t)b * 3 * 4096;
    if (t < 64) {
        int gr = t >> 3, gc = t & 7;
        const float* pb = pix + gr * 8 * 64 + gc * 8;
        float s = 0.f;
        #pragma unroll
        for (int ch = 0; ch < 3; ++ch)
            #pragma unroll
            for (int r = 0; r < 8; ++r)
                #pragma unroll
                for (int c = 0; c < 8; ++c) {
                    float x = pb[ch * 4096 + r * 64 + c];
                    s += x * x;
                }
        inv[t] = 1.f / fmaxf(sqrtf(s), 1e-8f);
    }
    __syncthreads();
    for (int i = t; i < 64 * 192; i += 256) {
        int p = i / 192, d = i - p * 192;
        int ch = d >> 6, r = (d >> 3) & 7, c = d & 7;
        int gr = p >> 3, gc = p & 7;
        float x = pix[ch * 4096 + (gr * 8 + r) * 64 + gc * 8 + c] * inv[p];
        __hip_bfloat16 h = __float2bfloat16(x);
        float hf = __bfloat162float(h);
        __hip_bfloat16 lo = __float2bfloat16(x - hf);
        size_t row = (size_t)b * 64 + p;
        Abf[row * KP + d]       = *(unsigned short*)&h;
        Abf[row * KP + 192 + d] = *(unsigned short*)&lo;
    }
}

// ---------------- prep: codebook -> bf16 hi/lo, [4096][384] ----------------
__global__ __launch_bounds__(256) void prep_codebook_kernel(
    const float* __restrict__ cb, unsigned short* __restrict__ Bbf)
{
    int i = blockIdx.x * 256 + threadIdx.x;
    if (i >= KCODES * PDIM) return;
    int n = i / PDIM, d = i - n * PDIM;
    float x = cb[i];
    __hip_bfloat16 h = __float2bfloat16(x);
    float hf = __bfloat162float(h);
    __hip_bfloat16 lo = __float2bfloat16(x - hf);
    Bbf[(size_t)n * KP + d]       = *(unsigned short*)&h;
    Bbf[(size_t)n * KP + 192 + d] = *(unsigned short*)&lo;
}

// ---------------- bf16 MFMA GEMM + fused packed-key top-2 ----------------
// 256x256 block tile, 8 waves (4M x 2N), wave tile 64x128, BK=32.
// Virtual K=576: A-pattern [hi|hi|lo], B-pattern [hi|lo|hi] => hi*hi + hi*lo + lo*hi.
// Counted-vmcnt pipeline: 4 LDS buffers, depth-3 prefetch, one
// {s_waitcnt vmcnt(8); s_barrier} per K-step; loads never drain in main loop.
__global__ __launch_bounds__(512, 2) void gemm_top2_kernel(
    const unsigned short* __restrict__ A, const unsigned short* __restrict__ B,
    float* __restrict__ o1v, int* __restrict__ o1i,
    float* __restrict__ o2v, int* __restrict__ o2i)
{
    __shared__ unsigned short As[4][8192];   // 4 x 16KB (256 rows x 32 k)
    __shared__ unsigned short Bs[4][8192];   // 4 x 16KB (256 cols x 32 k)

    const int t = threadIdx.x;          // 0..511
    const int w = t >> 6;               // wave 0..7
    const int l = t & 63;
    const int lo4 = l & 15, hi4 = l >> 4;
    const int wr = w >> 1, wc = w & 1;  // 4M x 2N wave grid
    const int m0 = blockIdx.x * 256;

    // staging: thread t covers 16B chunk t (rows 0..127) and 512+t (rows 128..255)
    const int srow = t >> 2;                      // 0..127
    const int kc   = (t & 3) ^ ((srow >> 1) & 3); // swizzled k-chunk (involution)
    const unsigned short* a0b = A + (size_t)(m0 + srow) * KP + kc * 8;
    const unsigned short* b0b = B + (size_t)srow * KP + kc * 8;

    // LDS read offsets (ushort units within one 8192-ushort buffer)
    int aoff[4], boff[8];
    #pragma unroll
    for (int rt = 0; rt < 4; ++rt) {
        int row = wr * 64 + rt * 16 + lo4;
        aoff[rt] = row * 32 + (hi4 ^ ((row >> 1) & 3)) * 8;
    }
    #pragma unroll
    for (int ct = 0; ct < 8; ++ct) {
        int col = wc * 128 + ct * 16 + lo4;
        boff[ct] = col * 32 + (hi4 ^ ((col >> 1) & 3)) * 8;
    }

    int t1k[16], t2k[16];
    #pragma unroll
    for (int e = 0; e < 16; ++e) { t1k[e] = (int)0x80000000; t2k[e] = (int)0x80000000; }

    auto STAGE = [&](int s) {
        int nt = s / NKS, kk = s - nt * NKS;
        int k0 = kk * 32;
        int kA = (k0 < 192) ? k0 : (k0 - 192);   // A: [hi|hi|lo]
        int kB = (k0 < 384) ? k0 : (k0 - 384);   // B: [hi|lo|hi]
        char* Ad = (char*)As[s & 3] + w * 1024;
        char* Bd = (char*)Bs[s & 3] + w * 1024;
        const unsigned short* ga = a0b + kA;
        const unsigned short* gb = b0b + nt * (256 * KP) + kB;
        gload_lds16(ga, Ad);
        gload_lds16(ga + 128 * KP, Ad + 8192);
        gload_lds16(gb, Bd);
        gload_lds16(gb + 128 * KP, Bd + 8192);
    };

    f32x4 acc[4][8];

    // prologue: 3 stages in flight (12 loads)
    STAGE(0); STAGE(1); STAGE(2);

    for (int s = 0; s < SSTEPS; ++s) {
        const int nt = s / NKS, kk = s - nt * NKS;

        // my stage-s loads landed (vmcnt), then all waves' (barrier).
        if (s < SSTEPS - 2)
            asm volatile("s_waitcnt vmcnt(8)\n\ts_barrier" ::: "memory");
        else if (s == SSTEPS - 2)
            asm volatile("s_waitcnt vmcnt(4)\n\ts_barrier" ::: "memory");
        else
            asm volatile("s_waitcnt vmcnt(0)\n\ts_barrier" ::: "memory");

        // prefetch 3 steps ahead (overwrites buffer last read at iter s-1; safe
        // because every wave passed this barrier only after finishing iter s-1 reads)
        if (s + 3 < SSTEPS) STAGE(s + 3);

        if (kk == 0) {
            #pragma unroll
            for (int i = 0; i < 4; ++i)
                #pragma unroll
                for (int j = 0; j < 8; ++j) acc[i][j] = (f32x4){0.f, 0.f, 0.f, 0.f};
        }

        const unsigned short* Ab = As[s & 3];
        const unsigned short* Bb = Bs[s & 3];
        bf16x8 af[4];
        #pragma unroll
        for (int rt = 0; rt < 4; ++rt) af[rt] = *(const bf16x8*)&Ab[aoff[rt]];

        __builtin_amdgcn_s_setprio(1);
        {
            bf16x8 bg[4];
            #pragma unroll
            for (int ct = 0; ct < 4; ++ct) bg[ct] = *(const bf16x8*)&Bb[boff[ct]];
            #pragma unroll
            for (int rt = 0; rt < 4; ++rt)
                #pragma unroll
                for (int ct = 0; ct < 4; ++ct)
                    acc[rt][ct] = __builtin_amdgcn_mfma_f32_16x16x32_bf16(af[rt], bg[ct], acc[rt][ct], 0, 0, 0);
        }
        {
            bf16x8 bg[4];
            #pragma unroll
            for (int ct = 0; ct < 4; ++ct) bg[ct] = *(const bf16x8*)&Bb[boff[ct + 4]];
            #pragma unroll
            for (int rt = 0; rt < 4; ++rt)
                #pragma unroll
                for (int ct = 0; ct < 4; ++ct)
                    acc[rt][ct + 4] = __builtin_amdgcn_mfma_f32_16x16x32_bf16(af[rt], bg[ct], acc[rt][ct + 4], 0, 0, 0);
        }
        __builtin_amdgcn_s_setprio(0);

        // fold candidates at the end of each column tile (7 low mantissa bits
        // carry (nt,ct); chop <= 1.5e-5 << 2e-4 fp64-refine gate)
        if (kk == NKS - 1) {
            #pragma unroll
            for (int ct = 0; ct < 8; ++ct) {
                const int inv7 = 0x7F ^ ((nt << 3) | ct);   // wave-uniform
                #pragma unroll
                for (int rt = 0; rt < 4; ++rt)
                    #pragma unroll
                    for (int r = 0; r < 4; ++r) {
                        int key = (__float_as_int(acc[rt][ct][r]) & ~0x7F) | inv7;
                        kfold(t1k[rt * 4 + r], t2k[rt * 4 + r], key);
                    }
            }
        }
    }

    // ---- decode keys -> (value, index) ----
    float p1v[16], p2v[16];
    int   p1i[16], p2i[16];
    #pragma unroll
    for (int e = 0; e < 16; ++e) {
        p1v[e] = __int_as_float(t1k[e] & ~0x7F);
        int lo7 = 0x7F ^ (t1k[e] & 0x7F);
        p1i[e] = ((lo7 >> 3) << 8) + wc * 128 + ((lo7 & 7) << 4) + lo4;
        p2v[e] = __int_as_float(t2k[e] & ~0x7F);
        int lo7b = 0x7F ^ (t2k[e] & 0x7F);
        p2i[e] = ((lo7b >> 3) << 8) + wc * 128 + ((lo7b & 7) << 4) + lo4;
    }

    // intra-wave butterfly top-2 reduce across the 16 col-lanes of each frag row
    #pragma unroll
    for (int e = 0; e < 16; ++e) {
        #pragma unroll
        for (int m = 1; m < 16; m <<= 1) {
            float ov1 = __shfl_xor(p1v[e], m);
            int   oi1 = __shfl_xor(p1i[e], m);
            float ov2 = __shfl_xor(p2v[e], m);
            int   oi2 = __shfl_xor(p2i[e], m);
            merge_top2(p1v[e], p1i[e], p2v[e], p2i[e], ov1, oi1, ov2, oi2);
        }
    }

    // cross-wave (column-half) merge via LDS scratch (reuse As; pipeline drained)
    __syncthreads();
    float* r1v = (float*)As;           // [256][2]
    float* r2v = r1v + 512;
    int*   r1i = (int*)(r2v + 512);
    int*   r2i = r1i + 512;
    if (lo4 == 0) {
        #pragma unroll
        for (int rt = 0; rt < 4; ++rt)
            #pragma unroll
            for (int r = 0; r < 4; ++r) {
                const int e = rt * 4 + r;
                int row = wr * 64 + rt * 16 + hi4 * 4 + r;   // 0..255
                r1v[row * 2 + wc] = p1v[e]; r1i[row * 2 + wc] = p1i[e];
                r2v[row * 2 + wc] = p2v[e]; r2i[row * 2 + wc] = p2i[e];
            }
    }
    __syncthreads();
    if (t < 256) {
        float v1 = r1v[t * 2], v2 = r2v[t * 2];
        int   i1 = r1i[t * 2], i2 = r2i[t * 2];
        merge_top2(v1, i1, v2, i2, r1v[t * 2 + 1], r1i[t * 2 + 1],
                                   r2v[t * 2 + 1], r2i[t * 2 + 1]);
        int grow = m0 + t;
        o1v[grow] = v1; o1i[grow] = i1;
        o2v[grow] = v2; o2i[grow] = i2;
    }
}

// ---------------- fp64 refinement of near-tie argmax ----------------
__global__ __launch_bounds__(256) void refine_kernel(
    const float* __restrict__ pixels, const float* __restrict__ codebook,
    const float* __restrict__ o1v, const int* __restrict__ o1i,
    const float* __restrict__ o2v, const int* __restrict__ o2i,
    int* __restrict__ idx_out, float* __restrict__ idxf_out)
{
    int row = blockIdx.x * 256 + threadIdx.x;
    if (row >= MROWS) return;
    float v1 = o1v[row], v2 = o2v[row];
    int   i1 = o1i[row], i2 = o2i[row];
    int idx = i1;
    if (v1 - v2 <= 2e-4f) {
        int b = row >> 6, p = row & 63;
        int gr = p >> 3, gc = p & 7;
        const float* pb = pixels + (size_t)b * 3 * 4096 + gr * 8 * 64 + gc * 8;
        const float* c1 = codebook + (size_t)i1 * PDIM;
        const float* c2 = codebook + (size_t)i2 * PDIM;
        double s1 = 0.0, s2 = 0.0;
        for (int d = 0; d < PDIM; ++d) {
            int ch = d >> 6, r = (d >> 3) & 7, c = d & 7;
            double x = (double)pb[ch * 4096 + r * 64 + c];
            s1 += x * (double)c1[d];
            s2 += x * (double)c2[d];
        }
        if (s2 > s1 || (s2 == s1 && i2 < i1)) idx = i2;
    }
    idx_out[row] = idx;
    idxf_out[row] = (float)idx;
}

// ---------------- z_real / z_local ----------------
__global__ __launch_bounds__(256) void zreal_kernel(
    const float* __restrict__ emb, const int* __restrict__ idx,
    float* __restrict__ z_real, float* __restrict__ z_local)
{
    __shared__ int sidx[64];
    int b = blockIdx.x, t = threadIdx.x;
    if (t < 64) sidx[t] = idx[b * 64 + t];
    __syncthreads();
    float s[8], sl[8];
    #pragma unroll
    for (int j = 0; j < 8; ++j) { s[j] = 0.f; sl[j] = 0.f; }
    for (int p = 0; p < 64; ++p) {
        int gr = p >> 3, gc = p & 7;
        bool ag = (gr >= 3 && gr < 6 && gc >= 3 && gc < 6);
        const float* er = emb + (size_t)sidx[p] * EDIM + t * 8;
        float v[8];
        *(float4*)&v[0] = *(const float4*)er;
        *(float4*)&v[4] = *(const float4*)(er + 4);
        #pragma unroll
        for (int j = 0; j < 8; ++j) s[j] += v[j];
        if (ag) {
            #pragma unroll
            for (int j = 0; j < 8; ++j) sl[j] += v[j];
        }
    }
    float* zr = z_real + (size_t)b * EDIM + t * 8;
    float* zl = z_local + (size_t)b * EDIM + t * 8;
    #pragma unroll
    for (int j = 0; j < 8; ++j) {
        zr[j] = s[j] * (1.f / 64.f);
        zl[j] = sl[j] * (1.f / 9.f);
    }
}

// ---------------- z_vsa ----------------
__global__ __launch_bounds__(256) void vsa_kernel(
    const float* __restrict__ vsa, const float* __restrict__ roles,
    const int* __restrict__ idx, float* __restrict__ z_vsa)
{
    __shared__ int cidx[16];
    int b = blockIdx.x, t = threadIdx.x;
    if (t < 16) {
        int p = (2 + (t >> 2)) * 8 + 2 + (t & 3);
        cidx[t] = idx[b * 64 + p];
    }
    __syncthreads();
    float cnt[8];
    #pragma unroll
    for (int j = 0; j < 8; ++j) cnt[j] = 0.f;
    for (int cp = 0; cp < 16; ++cp) {
        int p = (2 + (cp >> 2)) * 8 + 2 + (cp & 3);
        const float* vr = vsa + (size_t)cidx[cp] * VDIM + t * 8;
        const float* pr = roles + (size_t)p * VDIM + t * 8;
        float a[8], r[8];
        *(float4*)&a[0] = *(const float4*)vr;
        *(float4*)&a[4] = *(const float4*)(vr + 4);
        *(float4*)&r[0] = *(const float4*)pr;
        *(float4*)&r[4] = *(const float4*)(pr + 4);
        #pragma unroll
        for (int j = 0; j < 8; ++j) cnt[j] += (a[j] != r[j]) ? 1.f : 0.f;
    }
    #pragma unroll
    for (int j = 0; j < 8; ++j)
        z_vsa[(size_t)b * VDIM + t * 8 + j] = cnt[j] > 8.f ? 1.f : 0.f;
}

extern "C" void kernel_launch(void* const* d_in, const int* in_sizes, int n_in,
                              void* d_out, int out_size, void* d_ws, size_t ws_size,
                              hipStream_t stream) {
    const float* pixels         = (const float*)d_in[0];
    const float* codebook       = (const float*)d_in[1];
    const float* embeddings     = (const float*)d_in[2];
    const float* codebook_vsa   = (const float*)d_in[3];
    const float* position_roles = (const float*)d_in[4];

    float* out     = (float*)d_out;
    float* z_real  = out;                 // 1024*2048
    float* z_vsa   = out + 2097152;       // 1024*2048
    float* idxf    = out + 4194304;       // 1024*64
    float* z_local = out + 4259840;       // 1024*2048

    char* ws = (char*)d_ws;
    unsigned short* Abf = (unsigned short*)(ws);                     // 50331648 B
    unsigned short* Bbf = (unsigned short*)(ws + 50331648);          //  3145728 B
    float* o1v = (float*)(ws + 53477376);
    int*   o1i = (int*)  (ws + 54001664);
    float* o2v = (float*)(ws + 54525952);
    int*   o2i = (int*)  (ws + 55050240);
    int*   idxws = (int*)(ws + 55574528);

    prep_patches_kernel<<<NIMG, 256, 0, stream>>>(pixels, Abf);
    prep_codebook_kernel<<<(KCODES * PDIM + 255) / 256, 256, 0, stream>>>(codebook, Bbf);

    gemm_top2_kernel<<<MROWS / 256, 512, 0, stream>>>(Abf, Bbf, o1v, o1i, o2v, o2i);

    refine_kernel<<<MROWS / 256, 256, 0, stream>>>(pixels, codebook,
        o1v, o1i, o2v, o2i, idxws, idxf);
    zreal_kernel<<<NIMG, 256, 0, stream>>>(embeddings, idxws, z_real, z_local);
    vsa_kernel<<<NIMG, 256, 0, stream>>>(codebook_vsa, position_roles, idxws, z_vsa);
}

// Round 7
// 397.371 us; speedup vs baseline: 5.5876x; 1.1427x over previous
//
#include <hip/hip_runtime.h>
#include <hip/hip_bf16.h>
#include <math.h>

#define NIMG 1024
#define NPATCH 64
#define PDIM 192
#define KCODES 4096
#define EDIM 2048
#define VDIM 2048
#define MROWS (NIMG * NPATCH)   // 65536
#define KP 384                  // storage: [0,192)=hi, [192,384)=lo
#define NKS 18                  // K-steps (BK=32) per column tile: virtual K=576
#define NCT 16                  // column tiles of 256 codes
#define NKT (NCT * NKS)         // 288 flat K-steps

typedef __attribute__((ext_vector_type(8))) short bf16x8;
typedef __attribute__((ext_vector_type(4))) float f32x4;

__device__ __forceinline__ void gload_lds16(const void* g, void* l) {
    __builtin_amdgcn_global_load_lds(
        (const __attribute__((address_space(1))) unsigned int*)g,
        (__attribute__((address_space(3))) unsigned int*)l,
        16, 0, 0);
}

__device__ __forceinline__ void merge_top2(float& v1, int& i1, float& v2, int& i2,
                                           float ov1, int oi1, float ov2, int oi2) {
    bool aw = (v1 > ov1) || (v1 == ov1 && i1 < oi1);
    float w1v = aw ? v1 : ov1;  int w1i = aw ? i1 : oi1;
    float c2v = aw ? v2 : ov2;  int c2i = aw ? i2 : oi2;   // winner's own #2
    float l1v = aw ? ov1 : v1;  int l1i = aw ? oi1 : i1;   // loser's #1
    bool bw = (c2v > l1v) || (c2v == l1v && c2i < l1i);
    v1 = w1v; i1 = w1i;
    v2 = bw ? c2v : l1v; i2 = bw ? c2i : l1i;
}

// packed-key top-2 fold: 3 VALU (min_i32 + 2 max_i32)
__device__ __forceinline__ void kfold(int& t1, int& t2, int key) {
    int m = (key < t1) ? key : t1;
    t2 = (t2 > m) ? t2 : m;
    t1 = (t1 > key) ? t1 : key;
}

// ---------------- prep: normalized patches -> bf16 hi/lo, [65536][384] ----------------
__global__ __launch_bounds__(256) void prep_patches_kernel(
    const float* __restrict__ pixels, unsigned short* __restrict__ Abf)
{
    __shared__ float inv[64];
    const int b = blockIdx.x, t = threadIdx.x;
    const float* pix = pixels + (size_t)b * 3 * 4096;
    if (t < 64) {
        int gr = t >> 3, gc = t & 7;
        const float* pb = pix + gr * 8 * 64 + gc * 8;
        float s = 0.f;
        #pragma unroll
        for (int ch = 0; ch < 3; ++ch)
            #pragma unroll
            for (int r = 0; r < 8; ++r)
                #pragma unroll
                for (int c = 0; c < 8; ++c) {
                    float x = pb[ch * 4096 + r * 64 + c];
                    s += x * x;
                }
        inv[t] = 1.f / fmaxf(sqrtf(s), 1e-8f);
    }
    __syncthreads();
    for (int i = t; i < 64 * 192; i += 256) {
        int p = i / 192, d = i - p * 192;
        int ch = d >> 6, r = (d >> 3) & 7, c = d & 7;
        int gr = p >> 3, gc = p & 7;
        float x = pix[ch * 4096 + (gr * 8 + r) * 64 + gc * 8 + c] * inv[p];
        __hip_bfloat16 h = __float2bfloat16(x);
        float hf = __bfloat162float(h);
        __hip_bfloat16 lo = __float2bfloat16(x - hf);
        size_t row = (size_t)b * 64 + p;
        Abf[row * KP + d]       = *(unsigned short*)&h;
        Abf[row * KP + 192 + d] = *(unsigned short*)&lo;
    }
}

// ---------------- prep: codebook -> bf16 hi/lo, [4096][384] ----------------
__global__ __launch_bounds__(256) void prep_codebook_kernel(
    const float* __restrict__ cb, unsigned short* __restrict__ Bbf)
{
    int i = blockIdx.x * 256 + threadIdx.x;
    if (i >= KCODES * PDIM) return;
    int n = i / PDIM, d = i - n * PDIM;
    float x = cb[i];
    __hip_bfloat16 h = __float2bfloat16(x);
    float hf = __bfloat162float(h);
    __hip_bfloat16 lo = __float2bfloat16(x - hf);
    Bbf[(size_t)n * KP + d]       = *(unsigned short*)&h;
    Bbf[(size_t)n * KP + 192 + d] = *(unsigned short*)&lo;
}

// ---------------- bf16 MFMA GEMM + fused packed-key top-2 ----------------
// 256x256 block tile, 8 waves (4M x 2N), wave tile 64x128, BK=32.
// Virtual K=576: A [hi|hi|lo], B [hi|lo|hi] => hi*hi + hi*lo + lo*hi.
// 2-phase-per-K-step schedule (T3+T4): per phase {ds_read half ∥ stage issue,
// raw s_barrier (NO vmcnt drain), lgkmcnt(0)+sched_barrier, setprio MFMA x16}.
// 4 LDS buffers, stage distance 3, vmcnt(8) counted wait (tail: 4, 0).
__global__ __launch_bounds__(512) void gemm_top2_kernel(
    const unsigned short* __restrict__ A, const unsigned short* __restrict__ B,
    float* __restrict__ o1v, int* __restrict__ o1i,
    float* __restrict__ o2v, int* __restrict__ o2i)
{
    __shared__ unsigned short As[4][8192];   // 4 x 16KB (256 rows x 32 k)
    __shared__ unsigned short Bs[4][8192];   // 4 x 16KB (256 cols x 32 k)

    const int t = threadIdx.x;          // 0..511
    const int w = t >> 6;               // wave 0..7
    const int l = t & 63;
    const int lo4 = l & 15, hi4 = l >> 4;
    const int wr = w >> 1, wc = w & 1;  // 4M x 2N wave grid
    const int m0 = blockIdx.x * 256;

    // staging: thread t covers 16B chunk t (rows 0..127) and 512+t (rows 128..255)
    const int srow = t >> 2;                      // 0..127
    const int kc   = (t & 3) ^ ((srow >> 1) & 3); // swizzled k-chunk (involution)
    const unsigned short* a0b = A + (size_t)(m0 + srow) * KP + kc * 8;
    const unsigned short* b0b = B + (size_t)srow * KP + kc * 8;

    // LDS read offsets (ushort units within one 8192-ushort buffer)
    int aoff[4], boff[8];
    #pragma unroll
    for (int rt = 0; rt < 4; ++rt) {
        int row = wr * 64 + rt * 16 + lo4;
        aoff[rt] = row * 32 + (hi4 ^ ((row >> 1) & 3)) * 8;
    }
    #pragma unroll
    for (int cf = 0; cf < 8; ++cf) {
        int col = wc * 128 + cf * 16 + lo4;
        boff[cf] = col * 32 + (hi4 ^ ((col >> 1) & 3)) * 8;
    }

    int t1k[16], t2k[16];
    #pragma unroll
    for (int e = 0; e < 16; ++e) { t1k[e] = (int)0x80000000; t2k[e] = (int)0x80000000; }

    auto stageA = [&](int sj, int sbuf) {
        int k0 = sj * 32;
        int kA = (k0 < 192) ? k0 : (k0 - 192);   // A: [hi|hi|lo]
        char* Ad = (char*)As[sbuf] + w * 1024;
        const unsigned short* ga = a0b + kA;
        gload_lds16(ga, Ad);
        gload_lds16(ga + 128 * KP, Ad + 8192);
    };
    auto stageB = [&](int sct, int sj, int sbuf) {
        int k0 = sj * 32;
        int kB = (k0 < 384) ? k0 : (k0 - 384);   // B: [hi|lo|hi]
        char* Bd = (char*)Bs[sbuf] + w * 1024;
        const unsigned short* gb = b0b + sct * (256 * KP) + kB;
        gload_lds16(gb, Bd);
        gload_lds16(gb + 128 * KP, Bd + 8192);
    };

    // prologue: stage kt = 0,1,2 into bufs 0,1,2 (12 loads in flight)
    stageA(0, 0); stageB(0, 0, 0);
    stageA(1, 1); stageB(0, 1, 1);
    stageA(2, 2); stageB(0, 2, 2);

    f32x4 acc[4][8];
    int buf = 0;
    int stct = 0, stj = 3;   // stage target = kt+3 as (ct, j)

    for (int ct = 0; ct < NCT; ++ct) {
      for (int j = 0; j < NKS; ++j) {
        // ---------- phase 0 ----------
        // counted wait: my loads for THIS kt landed; kt+1/kt+2's stay in flight.
        if (ct == NCT - 1 && j >= NKS - 2) {
            if (j == NKS - 2) asm volatile("s_waitcnt vmcnt(4)" ::: "memory");
            else              asm volatile("s_waitcnt vmcnt(0)" ::: "memory");
        } else {
            asm volatile("s_waitcnt vmcnt(8)" ::: "memory");
        }
        __builtin_amdgcn_s_barrier();          // all waves: kt data valid,
        __builtin_amdgcn_sched_barrier(0);     // prev reads drained (lgkmcnt below)

        if (j == 0) {
            #pragma unroll
            for (int i = 0; i < 4; ++i)
                #pragma unroll
                for (int jj = 0; jj < 8; ++jj) acc[i][jj] = (f32x4){0.f, 0.f, 0.f, 0.f};
        }

        const unsigned short* Ab = As[buf];
        const unsigned short* Bb = Bs[buf];
        bf16x8 af[4], bg[4];
        #pragma unroll
        for (int rt = 0; rt < 4; ++rt) af[rt] = *(const bf16x8*)&Ab[aoff[rt]];
        #pragma unroll
        for (int cf = 0; cf < 4; ++cf) bg[cf] = *(const bf16x8*)&Bb[boff[cf]];
        if (stct < NCT) stageA(stj, (buf + 3) & 3);

        asm volatile("s_waitcnt lgkmcnt(0)" ::: "memory");
        __builtin_amdgcn_sched_barrier(0);
        __builtin_amdgcn_s_setprio(1);
        #pragma unroll
        for (int rt = 0; rt < 4; ++rt)
            #pragma unroll
            for (int cf = 0; cf < 4; ++cf)
                acc[rt][cf] = __builtin_amdgcn_mfma_f32_16x16x32_bf16(af[rt], bg[cf], acc[rt][cf], 0, 0, 0);
        __builtin_amdgcn_s_setprio(0);
        __builtin_amdgcn_sched_barrier(0);
        __builtin_amdgcn_s_barrier();

        // ---------- phase 1 ----------
        bf16x8 bh[4];
        #pragma unroll
        for (int cf = 0; cf < 4; ++cf) bh[cf] = *(const bf16x8*)&Bb[boff[cf + 4]];
        if (stct < NCT) stageB(stct, stj, (buf + 3) & 3);

        asm volatile("s_waitcnt lgkmcnt(0)" ::: "memory");
        __builtin_amdgcn_sched_barrier(0);
        __builtin_amdgcn_s_setprio(1);
        #pragma unroll
        for (int rt = 0; rt < 4; ++rt)
            #pragma unroll
            for (int cf = 0; cf < 4; ++cf)
                acc[rt][cf + 4] = __builtin_amdgcn_mfma_f32_16x16x32_bf16(af[rt], bh[cf], acc[rt][cf + 4], 0, 0, 0);
        __builtin_amdgcn_s_setprio(0);

        // fold candidates at the end of each column tile (7 low mantissa bits
        // carry (ct,cf); chop <= 1.5e-5 << 2e-4 fp64-refine gate)
        if (j == NKS - 1) {
            #pragma unroll
            for (int cf = 0; cf < 8; ++cf) {
                const int inv7 = 0x7F ^ ((ct << 3) | cf);   // wave-uniform
                #pragma unroll
                for (int rt = 0; rt < 4; ++rt)
                    #pragma unroll
                    for (int r = 0; r < 4; ++r) {
                        int key = (__float_as_int(acc[rt][cf][r]) & ~0x7F) | inv7;
                        kfold(t1k[rt * 4 + r], t2k[rt * 4 + r], key);
                    }
            }
        }

        if (stct < NCT && ++stj == NKS) { stj = 0; ++stct; }
        buf = (buf + 1) & 3;
      }
    }

    // ---- decode keys -> (value, index) ----
    float p1v[16], p2v[16];
    int   p1i[16], p2i[16];
    #pragma unroll
    for (int e = 0; e < 16; ++e) {
        p1v[e] = __int_as_float(t1k[e] & ~0x7F);
        int lo7 = 0x7F ^ (t1k[e] & 0x7F);
        p1i[e] = ((lo7 >> 3) << 8) + wc * 128 + ((lo7 & 7) << 4) + lo4;
        p2v[e] = __int_as_float(t2k[e] & ~0x7F);
        int lo7b = 0x7F ^ (t2k[e] & 0x7F);
        p2i[e] = ((lo7b >> 3) << 8) + wc * 128 + ((lo7b & 7) << 4) + lo4;
    }

    // intra-wave butterfly top-2 reduce across the 16 col-lanes of each frag row
    #pragma unroll
    for (int e = 0; e < 16; ++e) {
        #pragma unroll
        for (int m = 1; m < 16; m <<= 1) {
            float ov1 = __shfl_xor(p1v[e], m);
            int   oi1 = __shfl_xor(p1i[e], m);
            float ov2 = __shfl_xor(p2v[e], m);
            int   oi2 = __shfl_xor(p2i[e], m);
            merge_top2(p1v[e], p1i[e], p2v[e], p2i[e], ov1, oi1, ov2, oi2);
        }
    }

    // cross-wave (column-half) merge via LDS scratch (reuse As; pipeline drained)
    __syncthreads();
    float* r1v = (float*)As;           // [256][2]
    float* r2v = r1v + 512;
    int*   r1i = (int*)(r2v + 512);
    int*   r2i = r1i + 512;
    if (lo4 == 0) {
        #pragma unroll
        for (int rt = 0; rt < 4; ++rt)
            #pragma unroll
            for (int r = 0; r < 4; ++r) {
                const int e = rt * 4 + r;
                int row = wr * 64 + rt * 16 + hi4 * 4 + r;   // 0..255
                r1v[row * 2 + wc] = p1v[e]; r1i[row * 2 + wc] = p1i[e];
                r2v[row * 2 + wc] = p2v[e]; r2i[row * 2 + wc] = p2i[e];
            }
    }
    __syncthreads();
    if (t < 256) {
        float v1 = r1v[t * 2], v2 = r2v[t * 2];
        int   i1 = r1i[t * 2], i2 = r2i[t * 2];
        merge_top2(v1, i1, v2, i2, r1v[t * 2 + 1], r1i[t * 2 + 1],
                                   r2v[t * 2 + 1], r2i[t * 2 + 1]);
        int grow = m0 + t;
        o1v[grow] = v1; o1i[grow] = i1;
        o2v[grow] = v2; o2i[grow] = i2;
    }
}

// ---------------- fp64 refinement of near-tie argmax ----------------
__global__ __launch_bounds__(256) void refine_kernel(
    const float* __restrict__ pixels, const float* __restrict__ codebook,
    const float* __restrict__ o1v, const int* __restrict__ o1i,
    const float* __restrict__ o2v, const int* __restrict__ o2i,
    int* __restrict__ idx_out, float* __restrict__ idxf_out)
{
    int row = blockIdx.x * 256 + threadIdx.x;
    if (row >= MROWS) return;
    float v1 = o1v[row], v2 = o2v[row];
    int   i1 = o1i[row], i2 = o2i[row];
    int idx = i1;
    if (v1 - v2 <= 2e-4f) {
        int b = row >> 6, p = row & 63;
        int gr = p >> 3, gc = p & 7;
        const float* pb = pixels + (size_t)b * 3 * 4096 + gr * 8 * 64 + gc * 8;
        const float* c1 = codebook + (size_t)i1 * PDIM;
        const float* c2 = codebook + (size_t)i2 * PDIM;
        double s1 = 0.0, s2 = 0.0;
        for (int d = 0; d < PDIM; ++d) {
            int ch = d >> 6, r = (d >> 3) & 7, c = d & 7;
            double x = (double)pb[ch * 4096 + r * 64 + c];
            s1 += x * (double)c1[d];
            s2 += x * (double)c2[d];
        }
        if (s2 > s1 || (s2 == s1 && i2 < i1)) idx = i2;
    }
    idx_out[row] = idx;
    idxf_out[row] = (float)idx;
}

// ---------------- z_real / z_local ----------------
__global__ __launch_bounds__(256) void zreal_kernel(
    const float* __restrict__ emb, const int* __restrict__ idx,
    float* __restrict__ z_real, float* __restrict__ z_local)
{
    __shared__ int sidx[64];
    int b = blockIdx.x, t = threadIdx.x;
    if (t < 64) sidx[t] = idx[b * 64 + t];
    __syncthreads();
    float s[8], sl[8];
    #pragma unroll
    for (int j = 0; j < 8; ++j) { s[j] = 0.f; sl[j] = 0.f; }
    for (int p = 0; p < 64; ++p) {
        int gr = p >> 3, gc = p & 7;
        bool ag = (gr >= 3 && gr < 6 && gc >= 3 && gc < 6);
        const float* er = emb + (size_t)sidx[p] * EDIM + t * 8;
        float v[8];
        *(float4*)&v[0] = *(const float4*)er;
        *(float4*)&v[4] = *(const float4*)(er + 4);
        #pragma unroll
        for (int j = 0; j < 8; ++j) s[j] += v[j];
        if (ag) {
            #pragma unroll
            for (int j = 0; j < 8; ++j) sl[j] += v[j];
        }
    }
    float* zr = z_real + (size_t)b * EDIM + t * 8;
    float* zl = z_local + (size_t)b * EDIM + t * 8;
    #pragma unroll
    for (int j = 0; j < 8; ++j) {
        zr[j] = s[j] * (1.f / 64.f);
        zl[j] = sl[j] * (1.f / 9.f);
    }
}

// ---------------- z_vsa ----------------
__global__ __launch_bounds__(256) void vsa_kernel(
    const float* __restrict__ vsa, const float* __restrict__ roles,
    const int* __restrict__ idx, float* __restrict__ z_vsa)
{
    __shared__ int cidx[16];
    int b = blockIdx.x, t = threadIdx.x;
    if (t < 16) {
        int p = (2 + (t >> 2)) * 8 + 2 + (t & 3);
        cidx[t] = idx[b * 64 + p];
    }
    __syncthreads();
    float cnt[8];
    #pragma unroll
    for (int j = 0; j < 8; ++j) cnt[j] = 0.f;
    for (int cp = 0; cp < 16; ++cp) {
        int p = (2 + (cp >> 2)) * 8 + 2 + (cp & 3);
        const float* vr = vsa + (size_t)cidx[cp] * VDIM + t * 8;
        const float* pr = roles + (size_t)p * VDIM + t * 8;
        float a[8], r[8];
        *(float4*)&a[0] = *(const float4*)vr;
        *(float4*)&a[4] = *(const float4*)(vr + 4);
        *(float4*)&r[0] = *(const float4*)pr;
        *(float4*)&r[4] = *(const float4*)(pr + 4);
        #pragma unroll
        for (int j = 0; j < 8; ++j) cnt[j] += (a[j] != r[j]) ? 1.f : 0.f;
    }
    #pragma unroll
    for (int j = 0; j < 8; ++j)
        z_vsa[(size_t)b * VDIM + t * 8 + j] = cnt[j] > 8.f ? 1.f : 0.f;
}

extern "C" void kernel_launch(void* const* d_in, const int* in_sizes, int n_in,
                              void* d_out, int out_size, void* d_ws, size_t ws_size,
                              hipStream_t stream) {
    const float* pixels         = (const float*)d_in[0];
    const float* codebook       = (const float*)d_in[1];
    const float* embeddings     = (const float*)d_in[2];
    const float* codebook_vsa   = (const float*)d_in[3];
    const float* position_roles = (const float*)d_in[4];

    float* out     = (float*)d_out;
    float* z_real  = out;                 // 1024*2048
    float* z_vsa   = out + 2097152;       // 1024*2048
    float* idxf    = out + 4194304;       // 1024*64
    float* z_local = out + 4259840;       // 1024*2048

    char* ws = (char*)d_ws;
    unsigned short* Abf = (unsigned short*)(ws);                     // 50331648 B
    unsigned short* Bbf = (unsigned short*)(ws + 50331648);          //  3145728 B
    float* o1v = (float*)(ws + 53477376);
    int*   o1i = (int*)  (ws + 54001664);
    float* o2v = (float*)(ws + 54525952);
    int*   o2i = (int*)  (ws + 55050240);
    int*   idxws = (int*)(ws + 55574528);

    prep_patches_kernel<<<NIMG, 256, 0, stream>>>(pixels, Abf);
    prep_codebook_kernel<<<(KCODES * PDIM + 255) / 256, 256, 0, stream>>>(codebook, Bbf);

    gemm_top2_kernel<<<MROWS / 256, 512, 0, stream>>>(Abf, Bbf, o1v, o1i, o2v, o2i);

    refine_kernel<<<MROWS / 256, 256, 0, stream>>>(pixels, codebook,
        o1v, o1i, o2v, o2i, idxws, idxf);
    zreal_kernel<<<NIMG, 256, 0, stream>>>(embeddings, idxws, z_real, z_local);
    vsa_kernel<<<NIMG, 256, 0, stream>>>(codebook_vsa, position_roles, idxws, z_vsa);
}

// Round 8
// 363.284 us; speedup vs baseline: 6.1119x; 1.0938x over previous
//
#include <hip/hip_runtime.h>
#include <hip/hip_bf16.h>
#include <math.h>

#define NIMG 1024
#define NPATCH 64
#define PDIM 192
#define KCODES 4096
#define EDIM 2048
#define VDIM 2048
#define MROWS (NIMG * NPATCH)   // 65536
#define KP 384                  // storage: [0,192)=hi, [192,384)=lo
#define NKS 18                  // K-steps (BK=32) per column tile: virtual K=576
#define NCT 16                  // column tiles of 256 codes
#define NKT (NCT * NKS)         // 288 flat K-steps

typedef __attribute__((ext_vector_type(8))) short bf16x8;
typedef __attribute__((ext_vector_type(4))) float f32x4;

__device__ __forceinline__ void gload_lds16(const void* g, void* l) {
    __builtin_amdgcn_global_load_lds(
        (const __attribute__((address_space(1))) unsigned int*)g,
        (__attribute__((address_space(3))) unsigned int*)l,
        16, 0, 0);
}

__device__ __forceinline__ void merge_top2(float& v1, int& i1, float& v2, int& i2,
                                           float ov1, int oi1, float ov2, int oi2) {
    bool aw = (v1 > ov1) || (v1 == ov1 && i1 < oi1);
    float w1v = aw ? v1 : ov1;  int w1i = aw ? i1 : oi1;
    float c2v = aw ? v2 : ov2;  int c2i = aw ? i2 : oi2;   // winner's own #2
    float l1v = aw ? ov1 : v1;  int l1i = aw ? oi1 : i1;   // loser's #1
    bool bw = (c2v > l1v) || (c2v == l1v && c2i < l1i);
    v1 = w1v; i1 = w1i;
    v2 = bw ? c2v : l1v; i2 = bw ? c2i : l1i;
}

// packed-key top-2 fold: 3 VALU (min_i32 + 2 max_i32)
__device__ __forceinline__ void kfold(int& t1, int& t2, int key) {
    int m = (key < t1) ? key : t1;
    t2 = (t2 > m) ? t2 : m;
    t1 = (t1 > key) ? t1 : key;
}

// ---------------- prep: normalized patches -> bf16 hi/lo, [65536][384] ----------------
__global__ __launch_bounds__(256) void prep_patches_kernel(
    const float* __restrict__ pixels, unsigned short* __restrict__ Abf)
{
    __shared__ float inv[64];
    const int b = blockIdx.x, t = threadIdx.x;
    const float* pix = pixels + (size_t)b * 3 * 4096;
    if (t < 64) {
        int gr = t >> 3, gc = t & 7;
        const float* pb = pix + gr * 8 * 64 + gc * 8;
        float s = 0.f;
        #pragma unroll
        for (int ch = 0; ch < 3; ++ch)
            #pragma unroll
            for (int r = 0; r < 8; ++r)
                #pragma unroll
                for (int c = 0; c < 8; ++c) {
                    float x = pb[ch * 4096 + r * 64 + c];
                    s += x * x;
                }
        inv[t] = 1.f / fmaxf(sqrtf(s), 1e-8f);
    }
    __syncthreads();
    for (int i = t; i < 64 * 192; i += 256) {
        int p = i / 192, d = i - p * 192;
        int ch = d >> 6, r = (d >> 3) & 7, c = d & 7;
        int gr = p >> 3, gc = p & 7;
        float x = pix[ch * 4096 + (gr * 8 + r) * 64 + gc * 8 + c] * inv[p];
        __hip_bfloat16 h = __float2bfloat16(x);
        float hf = __bfloat162float(h);
        __hip_bfloat16 lo = __float2bfloat16(x - hf);
        size_t row = (size_t)b * 64 + p;
        Abf[row * KP + d]       = *(unsigned short*)&h;
        Abf[row * KP + 192 + d] = *(unsigned short*)&lo;
    }
}

// ---------------- prep: codebook -> bf16 hi/lo, [4096][384] ----------------
__global__ __launch_bounds__(256) void prep_codebook_kernel(
    const float* __restrict__ cb, unsigned short* __restrict__ Bbf)
{
    int i = blockIdx.x * 256 + threadIdx.x;
    if (i >= KCODES * PDIM) return;
    int n = i / PDIM, d = i - n * PDIM;
    float x = cb[i];
    __hip_bfloat16 h = __float2bfloat16(x);
    float hf = __bfloat162float(h);
    __hip_bfloat16 lo = __float2bfloat16(x - hf);
    Bbf[(size_t)n * KP + d]       = *(unsigned short*)&h;
    Bbf[(size_t)n * KP + 192 + d] = *(unsigned short*)&lo;
}

// ---------------- bf16 MFMA GEMM + fused packed-key top-2 ----------------
// 256x256 block tile, 8 waves (4M x 2N), wave tile 64x128, BK=32.
// Virtual K=576: A [hi|hi|lo], B [hi|lo|hi] => hi*hi + hi*lo + lo*hi.
// Late-validation schedule: ONE {vmcnt(8); s_barrier} at END of step s
// validates buf[(s+1)&3], so step s+1's ds_reads issue with NO wait and
// overlap other waves' step-s MFMA tail. 4 LDS buffers, stage distance 3.
__global__ __launch_bounds__(512) void gemm_top2_kernel(
    const unsigned short* __restrict__ A, const unsigned short* __restrict__ B,
    float* __restrict__ o1v, int* __restrict__ o1i,
    float* __restrict__ o2v, int* __restrict__ o2i)
{
    __shared__ unsigned short As[4][8192];   // 4 x 16KB (256 rows x 32 k)
    __shared__ unsigned short Bs[4][8192];   // 4 x 16KB (256 cols x 32 k)

    const int t = threadIdx.x;          // 0..511
    const int w = t >> 6;               // wave 0..7
    const int l = t & 63;
    const int lo4 = l & 15, hi4 = l >> 4;
    const int wr = w >> 1, wc = w & 1;  // 4M x 2N wave grid
    const int m0 = blockIdx.x * 256;

    // staging: thread t covers 16B chunk t (rows 0..127) and 512+t (rows 128..255)
    const int srow = t >> 2;                      // 0..127
    const int kc   = (t & 3) ^ ((srow >> 1) & 3); // swizzled k-chunk (involution)
    const unsigned short* a0b = A + (size_t)(m0 + srow) * KP + kc * 8;
    const unsigned short* b0b = B + (size_t)srow * KP + kc * 8;

    // LDS read offsets (ushort units within one 8192-ushort buffer)
    int aoff[4], boff[8];
    #pragma unroll
    for (int rt = 0; rt < 4; ++rt) {
        int row = wr * 64 + rt * 16 + lo4;
        aoff[rt] = row * 32 + (hi4 ^ ((row >> 1) & 3)) * 8;
    }
    #pragma unroll
    for (int cf = 0; cf < 8; ++cf) {
        int col = wc * 128 + cf * 16 + lo4;
        boff[cf] = col * 32 + (hi4 ^ ((col >> 1) & 3)) * 8;
    }

    int t1k[16], t2k[16];
    #pragma unroll
    for (int e = 0; e < 16; ++e) { t1k[e] = (int)0x80000000; t2k[e] = (int)0x80000000; }

    auto stageA = [&](int sj, int sbuf) {
        int k0 = sj * 32;
        int kA = (k0 < 192) ? k0 : (k0 - 192);   // A: [hi|hi|lo]
        char* Ad = (char*)As[sbuf] + w * 1024;
        const unsigned short* ga = a0b + kA;
        gload_lds16(ga, Ad);
        gload_lds16(ga + 128 * KP, Ad + 8192);
    };
    auto stageB = [&](int sct, int sj, int sbuf) {
        int k0 = sj * 32;
        int kB = (k0 < 384) ? k0 : (k0 - 384);   // B: [hi|lo|hi]
        char* Bd = (char*)Bs[sbuf] + w * 1024;
        const unsigned short* gb = b0b + sct * (256 * KP) + kB;
        gload_lds16(gb, Bd);
        gload_lds16(gb + 128 * KP, Bd + 8192);
    };

    // prologue: stage kt = 0,1,2 into bufs 0,1,2 (12 loads in flight);
    // vmcnt(8) => my stage-0 loads landed; barrier => everyone's.
    stageA(0, 0); stageB(0, 0, 0);
    stageA(1, 1); stageB(0, 1, 1);
    stageA(2, 2); stageB(0, 2, 2);
    asm volatile("s_waitcnt vmcnt(8)\n\ts_barrier" ::: "memory");

    f32x4 acc[4][8];
    int buf = 0;
    int stct = 0, stj = 3;   // stage target = s+3 as (ct, j)

    for (int ct = 0; ct < NCT; ++ct) {
      for (int j = 0; j < NKS; ++j) {
        const unsigned short* Ab = As[buf];
        const unsigned short* Bb = Bs[buf];
        const int sbuf = (buf + 3) & 3;

        // ---------- phase 0 ----------
        // buf was validated at the END barrier of the previous step:
        // reads issue immediately, overlapping other waves' previous MFMA.
        bf16x8 af[4], bg[4];
        #pragma unroll
        for (int rt = 0; rt < 4; ++rt) af[rt] = *(const bf16x8*)&Ab[aoff[rt]];
        #pragma unroll
        for (int cf = 0; cf < 4; ++cf) bg[cf] = *(const bf16x8*)&Bb[boff[cf]];
        // stage(s+3) overwrites buf[(s-1)&3]; all waves finished reading it
        // before the previous end-barrier => clobber-safe.
        if (stct < NCT) stageA(stj, sbuf);

        if (j == 0) {
            #pragma unroll
            for (int i = 0; i < 4; ++i)
                #pragma unroll
                for (int jj = 0; jj < 8; ++jj) acc[i][jj] = (f32x4){0.f, 0.f, 0.f, 0.f};
        }

        asm volatile("s_waitcnt lgkmcnt(0)" ::: "memory");
        __builtin_amdgcn_sched_barrier(0);
        __builtin_amdgcn_s_setprio(1);
        #pragma unroll
        for (int rt = 0; rt < 4; ++rt)
            #pragma unroll
            for (int cf = 0; cf < 4; ++cf)
                acc[rt][cf] = __builtin_amdgcn_mfma_f32_16x16x32_bf16(af[rt], bg[cf], acc[rt][cf], 0, 0, 0);
        __builtin_amdgcn_s_setprio(0);

        // ---------- phase 1 ----------
        bf16x8 bh[4];
        #pragma unroll
        for (int cf = 0; cf < 4; ++cf) bh[cf] = *(const bf16x8*)&Bb[boff[cf + 4]];
        if (stct < NCT) stageB(stct, stj, sbuf);

        // fold first half (acc[.][0..3] complete after phase-0 MFMA);
        // overlaps the bh ds_read latency.
        if (j == NKS - 1) {
            #pragma unroll
            for (int cf = 0; cf < 4; ++cf) {
                const int inv7 = 0x7F ^ ((ct << 3) | cf);   // wave-uniform
                #pragma unroll
                for (int rt = 0; rt < 4; ++rt)
                    #pragma unroll
                    for (int r = 0; r < 4; ++r) {
                        int key = (__float_as_int(acc[rt][cf][r]) & ~0x7F) | inv7;
                        kfold(t1k[rt * 4 + r], t2k[rt * 4 + r], key);
                    }
            }
        }

        asm volatile("s_waitcnt lgkmcnt(0)" ::: "memory");
        __builtin_amdgcn_sched_barrier(0);
        __builtin_amdgcn_s_setprio(1);
        #pragma unroll
        for (int rt = 0; rt < 4; ++rt)
            #pragma unroll
            for (int cf = 0; cf < 4; ++cf)
                acc[rt][cf + 4] = __builtin_amdgcn_mfma_f32_16x16x32_bf16(af[rt], bh[cf], acc[rt][cf + 4], 0, 0, 0);
        __builtin_amdgcn_s_setprio(0);
        __builtin_amdgcn_sched_barrier(0);

        // ---------- end-of-step sync: validate buf[(s+1)&3] ----------
        // outstanding stages at this point: {s+1, s+2, s+3} (4 loads each,
        // clipped at NKT-1). Wait so that stage(s+1) has landed.
        if (ct < NCT - 1 || j < NKS - 3) {
            asm volatile("s_waitcnt vmcnt(8)\n\ts_barrier" ::: "memory");
        } else if (j == NKS - 3) {
            asm volatile("s_waitcnt vmcnt(4)\n\ts_barrier" ::: "memory");
        } else if (j == NKS - 2) {
            asm volatile("s_waitcnt vmcnt(0)\n\ts_barrier" ::: "memory");
        } // last step: no barrier (epilogue __syncthreads covers)

        // fold second half after the barrier (pure-register; interleaves
        // with next step's phase-0 ds_reads).
        if (j == NKS - 1) {
            #pragma unroll
            for (int cf = 4; cf < 8; ++cf) {
                const int inv7 = 0x7F ^ ((ct << 3) | cf);
                #pragma unroll
                for (int rt = 0; rt < 4; ++rt)
                    #pragma unroll
                    for (int r = 0; r < 4; ++r) {
                        int key = (__float_as_int(acc[rt][cf][r]) & ~0x7F) | inv7;
                        kfold(t1k[rt * 4 + r], t2k[rt * 4 + r], key);
                    }
            }
        }

        if (stct < NCT && ++stj == NKS) { stj = 0; ++stct; }
        buf = (buf + 1) & 3;
      }
    }

    // ---- decode keys -> (value, index) ----
    float p1v[16], p2v[16];
    int   p1i[16], p2i[16];
    #pragma unroll
    for (int e = 0; e < 16; ++e) {
        p1v[e] = __int_as_float(t1k[e] & ~0x7F);
        int lo7 = 0x7F ^ (t1k[e] & 0x7F);
        p1i[e] = ((lo7 >> 3) << 8) + wc * 128 + ((lo7 & 7) << 4) + lo4;
        p2v[e] = __int_as_float(t2k[e] & ~0x7F);
        int lo7b = 0x7F ^ (t2k[e] & 0x7F);
        p2i[e] = ((lo7b >> 3) << 8) + wc * 128 + ((lo7b & 7) << 4) + lo4;
    }

    // intra-wave butterfly top-2 reduce across the 16 col-lanes of each frag row
    #pragma unroll
    for (int e = 0; e < 16; ++e) {
        #pragma unroll
        for (int m = 1; m < 16; m <<= 1) {
            float ov1 = __shfl_xor(p1v[e], m);
            int   oi1 = __shfl_xor(p1i[e], m);
            float ov2 = __shfl_xor(p2v[e], m);
            int   oi2 = __shfl_xor(p2i[e], m);
            merge_top2(p1v[e], p1i[e], p2v[e], p2i[e], ov1, oi1, ov2, oi2);
        }
    }

    // cross-wave (column-half) merge via LDS scratch (reuse As; pipeline drained)
    __syncthreads();
    float* r1v = (float*)As;           // [256][2]
    float* r2v = r1v + 512;
    int*   r1i = (int*)(r2v + 512);
    int*   r2i = r1i + 512;
    if (lo4 == 0) {
        #pragma unroll
        for (int rt = 0; rt < 4; ++rt)
            #pragma unroll
            for (int r = 0; r < 4; ++r) {
                const int e = rt * 4 + r;
                int row = wr * 64 + rt * 16 + hi4 * 4 + r;   // 0..255
                r1v[row * 2 + wc] = p1v[e]; r1i[row * 2 + wc] = p1i[e];
                r2v[row * 2 + wc] = p2v[e]; r2i[row * 2 + wc] = p2i[e];
            }
    }
    __syncthreads();
    if (t < 256) {
        float v1 = r1v[t * 2], v2 = r2v[t * 2];
        int   i1 = r1i[t * 2], i2 = r2i[t * 2];
        merge_top2(v1, i1, v2, i2, r1v[t * 2 + 1], r1i[t * 2 + 1],
                                   r2v[t * 2 + 1], r2i[t * 2 + 1]);
        int grow = m0 + t;
        o1v[grow] = v1; o1i[grow] = i1;
        o2v[grow] = v2; o2i[grow] = i2;
    }
}

// ---------------- fp64 refinement of near-tie argmax ----------------
__global__ __launch_bounds__(256) void refine_kernel(
    const float* __restrict__ pixels, const float* __restrict__ codebook,
    const float* __restrict__ o1v, const int* __restrict__ o1i,
    const float* __restrict__ o2v, const int* __restrict__ o2i,
    int* __restrict__ idx_out, float* __restrict__ idxf_out)
{
    int row = blockIdx.x * 256 + threadIdx.x;
    if (row >= MROWS) return;
    float v1 = o1v[row], v2 = o2v[row];
    int   i1 = o1i[row], i2 = o2i[row];
    int idx = i1;
    if (v1 - v2 <= 2e-4f) {
        int b = row >> 6, p = row & 63;
        int gr = p >> 3, gc = p & 7;
        const float* pb = pixels + (size_t)b * 3 * 4096 + gr * 8 * 64 + gc * 8;
        const float* c1 = codebook + (size_t)i1 * PDIM;
        const float* c2 = codebook + (size_t)i2 * PDIM;
        double s1 = 0.0, s2 = 0.0;
        for (int d = 0; d < PDIM; ++d) {
            int ch = d >> 6, r = (d >> 3) & 7, c = d & 7;
            double x = (double)pb[ch * 4096 + r * 64 + c];
            s1 += x * (double)c1[d];
            s2 += x * (double)c2[d];
        }
        if (s2 > s1 || (s2 == s1 && i2 < i1)) idx = i2;
    }
    idx_out[row] = idx;
    idxf_out[row] = (float)idx;
}

// ---------------- z_real / z_local ----------------
__global__ __launch_bounds__(256) void zreal_kernel(
    const float* __restrict__ emb, const int* __restrict__ idx,
    float* __restrict__ z_real, float* __restrict__ z_local)
{
    __shared__ int sidx[64];
    int b = blockIdx.x, t = threadIdx.x;
    if (t < 64) sidx[t] = idx[b * 64 + t];
    __syncthreads();
    float s[8], sl[8];
    #pragma unroll
    for (int j = 0; j < 8; ++j) { s[j] = 0.f; sl[j] = 0.f; }
    for (int p = 0; p < 64; ++p) {
        int gr = p >> 3, gc = p & 7;
        bool ag = (gr >= 3 && gr < 6 && gc >= 3 && gc < 6);
        const float* er = emb + (size_t)sidx[p] * EDIM + t * 8;
        float v[8];
        *(float4*)&v[0] = *(const float4*)er;
        *(float4*)&v[4] = *(const float4*)(er + 4);
        #pragma unroll
        for (int j = 0; j < 8; ++j) s[j] += v[j];
        if (ag) {
            #pragma unroll
            for (int j = 0; j < 8; ++j) sl[j] += v[j];
        }
    }
    float* zr = z_real + (size_t)b * EDIM + t * 8;
    float* zl = z_local + (size_t)b * EDIM + t * 8;
    #pragma unroll
    for (int j = 0; j < 8; ++j) {
        zr[j] = s[j] * (1.f / 64.f);
        zl[j] = sl[j] * (1.f / 9.f);
    }
}

// ---------------- z_vsa ----------------
__global__ __launch_bounds__(256) void vsa_kernel(
    const float* __restrict__ vsa, const float* __restrict__ roles,
    const int* __restrict__ idx, float* __restrict__ z_vsa)
{
    __shared__ int cidx[16];
    int b = blockIdx.x, t = threadIdx.x;
    if (t < 16) {
        int p = (2 + (t >> 2)) * 8 + 2 + (t & 3);
        cidx[t] = idx[b * 64 + p];
    }
    __syncthreads();
    float cnt[8];
    #pragma unroll
    for (int j = 0; j < 8; ++j) cnt[j] = 0.f;
    for (int cp = 0; cp < 16; ++cp) {
        int p = (2 + (cp >> 2)) * 8 + 2 + (cp & 3);
        const float* vr = vsa + (size_t)cidx[cp] * VDIM + t * 8;
        const float* pr = roles + (size_t)p * VDIM + t * 8;
        float a[8], r[8];
        *(float4*)&a[0] = *(const float4*)vr;
        *(float4*)&a[4] = *(const float4*)(vr + 4);
        *(float4*)&r[0] = *(const float4*)pr;
        *(float4*)&r[4] = *(const float4*)(pr + 4);
        #pragma unroll
        for (int j = 0; j < 8; ++j) cnt[j] += (a[j] != r[j]) ? 1.f : 0.f;
    }
    #pragma unroll
    for (int j = 0; j < 8; ++j)
        z_vsa[(size_t)b * VDIM + t * 8 + j] = cnt[j] > 8.f ? 1.f : 0.f;
}

extern "C" void kernel_launch(void* const* d_in, const int* in_sizes, int n_in,
                              void* d_out, int out_size, void* d_ws, size_t ws_size,
                              hipStream_t stream) {
    const float* pixels         = (const float*)d_in[0];
    const float* codebook       = (const float*)d_in[1];
    const float* embeddings     = (const float*)d_in[2];
    const float* codebook_vsa   = (const float*)d_in[3];
    const float* position_roles = (const float*)d_in[4];

    float* out     = (float*)d_out;
    float* z_real  = out;                 // 1024*2048
    float* z_vsa   = out + 2097152;       // 1024*2048
    float* idxf    = out + 4194304;       // 1024*64
    float* z_local = out + 4259840;       // 1024*2048

    char* ws = (char*)d_ws;
    unsigned short* Abf = (unsigned short*)(ws);                     // 50331648 B
    unsigned short* Bbf = (unsigned short*)(ws + 50331648);          //  3145728 B
    float* o1v = (float*)(ws + 53477376);
    int*   o1i = (int*)  (ws + 54001664);
    float* o2v = (float*)(ws + 54525952);
    int*   o2i = (int*)  (ws + 55050240);
    int*   idxws = (int*)(ws + 55574528);

    prep_patches_kernel<<<NIMG, 256, 0, stream>>>(pixels, Abf);
    prep_codebook_kernel<<<(KCODES * PDIM + 255) / 256, 256, 0, stream>>>(codebook, Bbf);

    gemm_top2_kernel<<<MROWS / 256, 512, 0, stream>>>(Abf, Bbf, o1v, o1i, o2v, o2i);

    refine_kernel<<<MROWS / 256, 256, 0, stream>>>(pixels, codebook,
        o1v, o1i, o2v, o2i, idxws, idxf);
    zreal_kernel<<<NIMG, 256, 0, stream>>>(embeddings, idxws, z_real, z_local);
    vsa_kernel<<<NIMG, 256, 0, stream>>>(codebook_vsa, position_roles, idxws, z_vsa);
}